// Round 5
// baseline (586.910 us; speedup 1.0000x reference)
//
#include <hip/hip_runtime.h>
#include <math.h>

#define BB 256
#define NAA 64
#define NTOK 65
#define DD 512
#define KK2 1024          // split-A doubled K
#define HH 16
#define HDD 32
#define NGEFF 4           // bond values 0..15 -> bits 4,5 of (bond-1) always 0; table row 0 is 0
#define MAXP 50

typedef short bf16x8 __attribute__((ext_vector_type(8)));
typedef float f32x4 __attribute__((ext_vector_type(4)));

static __device__ __forceinline__ unsigned short f2b_rne(float f) {
    unsigned u = __float_as_uint(f);
    unsigned r = (u + 0x7FFFu + ((u >> 16) & 1u)) >> 16;
    return (unsigned short)r;
}
static __device__ __forceinline__ float b2f(unsigned short u) {
    return __uint_as_float(((unsigned)u) << 16);
}
static __device__ __forceinline__ void gload16(const void* g, void* l) {
    __builtin_amdgcn_global_load_lds(
        (const __attribute__((address_space(1))) unsigned int*)g,
        (__attribute__((address_space(3))) unsigned int*)l, 16, 0, 0);
}

// ---------------------------------------------------------------- weight convert+duplicate
__global__ __launch_bounds__(256)
void k_cvt_wdup(const float* __restrict__ w, unsigned short* __restrict__ w2, int n)
{
    int i = blockIdx.x * 256 + threadIdx.x;
    if (i >= n) return;
    int row = i >> 9, k = i & 511;
    unsigned short v = f2b_rne(w[i]);
    w2[(size_t)row * KK2 + k] = v;
    w2[(size_t)row * KK2 + k + 512] = v;
}

// ---------------------------------------------------------------- atom embed -> split bf16
__global__ __launch_bounds__(256)
void k_atom_embed(const int* __restrict__ atom_fea,          // [B][7][64]
                  const float* __restrict__ atom_tables,     // [6][100][512]
                  const float* __restrict__ ga_means,        // [512]
                  const float* __restrict__ ga_stds,
                  const float* __restrict__ ga_mul,
                  const float* __restrict__ ga_bias,
                  const float* __restrict__ graph_token,     // [512]
                  unsigned short* __restrict__ x2)           // [B*65][1024] hi|lo
{
    int n = blockIdx.x;   // 0..64
    int b = blockIdx.y;
    int tid = threadIdx.x;
    unsigned short* xp = x2 + ((size_t)b * NTOK + n) * KK2;
    if (n == 0) {
        for (int d = tid; d < DD; d += 256) {
            float val = graph_token[d];
            unsigned short h = f2b_rne(val);
            xp[d] = h;
            xp[d + 512] = f2b_rne(val - b2f(h));
        }
        return;
    }
    int a = n - 1;
    int fea[6];
#pragma unroll
    for (int i = 0; i < 6; ++i) fea[i] = atom_fea[((b * 7) + i) * NAA + a];
    int ci = atom_fea[((b * 7) + 6) * NAA + a];
    float cont = (float)ci;
    float g = ga_mul[0] * cont + ga_bias[0];
    const float Ac = 2.5066268f;    // sqrt(2*3.14159)
    for (int d = tid; d < DD; d += 256) {
        float val = 0.f;
        if (ci != 0) {
            float sd = fabsf(ga_stds[d]) + 1e-5f;
            float t = (g - ga_means[d]) / sd;
            val = expf(-0.5f * t * t) / (Ac * sd);
        }
#pragma unroll
        for (int i = 0; i < 6; ++i)
            val += atom_tables[((i * 100) + fea[i]) * DD + d];
        unsigned short h = f2b_rne(val);
        xp[d] = h;
        xp[d + 512] = f2b_rne(val - b2f(h));
    }
}

// ---------------------------------------------------------------- edge bias (fully LDS-resident)
__global__ __launch_bounds__(1024)
void k_edge_bias(const int* __restrict__ bond_adj,           // [B][64][64]
                 const float* __restrict__ dist_adj,         // [B][64][64]
                 const float* __restrict__ edge_tables,      // [6][51][16]
                 const float* __restrict__ gb_means,         // [16]
                 const float* __restrict__ gb_stds,
                 const float* __restrict__ gb_mul,
                 const float* __restrict__ gb_bias,
                 const float* __restrict__ egt,              // [16]
                 float* __restrict__ biasb)                  // [B][16][65][65]
{
    int b = blockIdx.x;
    int tid = threadIdx.x;
    __shared__ float s_j[64 * 65];
    __shared__ float s_jn[64 * 65];
    __shared__ unsigned long long s_brow[64];
    __shared__ unsigned char s_idx[16][4096];      // [t*4+hop][p]
    __shared__ float s_et[4][51][17];
    __shared__ int s_bond[4096];
    __shared__ float s_gmn[16], s_gis[16], s_gcf[16], s_egt[16];

    const int* badj = bond_adj + (size_t)b * 4096;
    const float Ac = 2.5066268f;

    for (int q = tid; q < 4096; q += 1024) s_bond[q] = badj[q];
    for (int q = tid; q < 4 * 51 * 16; q += 1024) {
        int t = q >> 4;
        int hh = q & 15;
        s_et[t / 51][t % 51][hh] = edge_tables[q];
    }
    if (tid < 16) {
        float sd = fabsf(gb_stds[tid]) + 1e-5f;
        s_gmn[tid] = gb_means[tid];
        s_gis[tid] = 1.f / sd;
        s_gcf[tid] = 1.f / (Ac * sd);
        s_egt[tid] = egt[tid];
    }
    __syncthreads();

    for (int t = 0; t < NGEFF; ++t) {
        for (int q = tid; q < 4096; q += 1024) {
            int bd = s_bond[q];
            int bit = (bd > 0) ? ((bd - 1) >> t) & 1 : 0;
            unsigned long long m = __ballot(bit != 0);
            if ((q & 63) == 0) s_brow[q >> 6] = m;
            s_j[(q >> 6) * 65 + (q & 63)] = (float)bit;
            s_idx[t * 4][q] = (unsigned char)bit;
        }
        __syncthreads();
        float* cur = s_j;
        float* nxt = s_jn;
        for (int hop = 1; hop < 4; ++hop) {
            int r = tid >> 4;
            int c0 = (tid & 15) << 2;
            float a0 = 0.f, a1 = 0.f, a2 = 0.f, a3 = 0.f;
            for (int k = 0; k < 64; ++k) {
                float jv = cur[r * 65 + k];
                unsigned int rs = (unsigned int)(s_brow[k] >> c0);
                a0 += (rs & 1u) ? jv : 0.f;
                a1 += (rs & 2u) ? jv : 0.f;
                a2 += (rs & 4u) ? jv : 0.f;
                a3 += (rs & 8u) ? jv : 0.f;
            }
            nxt[r * 65 + c0 + 0] = a0;
            nxt[r * 65 + c0 + 1] = a1;
            nxt[r * 65 + c0 + 2] = a2;
            nxt[r * 65 + c0 + 3] = a3;
            int p0 = r * 64 + c0;
            int i0 = (int)a0; if (i0 > MAXP) i0 = MAXP;
            int i1 = (int)a1; if (i1 > MAXP) i1 = MAXP;
            int i2 = (int)a2; if (i2 > MAXP) i2 = MAXP;
            int i3 = (int)a3; if (i3 > MAXP) i3 = MAXP;
            s_idx[t * 4 + hop][p0 + 0] = (unsigned char)i0;
            s_idx[t * 4 + hop][p0 + 1] = (unsigned char)i1;
            s_idx[t * 4 + hop][p0 + 2] = (unsigned char)i2;
            s_idx[t * 4 + hop][p0 + 3] = (unsigned char)i3;
            __syncthreads();
            float* tmp = cur; cur = nxt; nxt = tmp;
        }
    }

    float* bb = biasb + (size_t)b * HH * NTOK * NTOK;
    for (int i = tid; i < HH * NTOK; i += 1024) {
        int hh = i / NTOK, j = i - hh * NTOK;
        float e = s_egt[hh];
        bb[(hh * NTOK + 0) * NTOK + j] = e;
        bb[(hh * NTOK + j) * NTOK + 0] = e;
    }
    float gm = gb_mul[0], gbi = gb_bias[0];
    for (int p = tid; p < 4096; p += 1024) {
        int a1i = p >> 6, a2i = p & 63;
        float dist = dist_adj[(size_t)b * 4096 + p];
        float g = gm * dist + gbi;
        float mv = (s_bond[p] != 0) ? 0.f : -INFINITY;
        int ixs[16];
#pragma unroll
        for (int q = 0; q < 16; ++q) ixs[q] = s_idx[q][p];
#pragma unroll
        for (int hh = 0; hh < 16; ++hh) {
            float v = 0.f;
            if (dist != 0.f) {
                float tt = (g - s_gmn[hh]) * s_gis[hh];
                v = expf(-0.5f * tt * tt) * s_gcf[hh];
            }
#pragma unroll
            for (int q = 0; q < 16; ++q) v += s_et[q >> 2][ixs[q]][hh];
            bb[(hh * NTOK + a1i + 1) * NTOK + (a2i + 1)] = v + mv;
        }
    }
}

// ---------------------------------------------------------------- MFMA GEMM
#define TM 128
#define TN 128
#define TBK 32
__global__ __launch_bounds__(256)
void k_gemm_mfma(const unsigned short* __restrict__ A,
                 const unsigned short* __restrict__ W,
                 const float* __restrict__ bias,
                 float* __restrict__ C,
                 int M, int N, int KK)
{
    __shared__ short sA[TM * TBK];   // 8 KB
    __shared__ short sB[TN * TBK];   // 8 KB
    int tid = threadIdx.x;
    int lane = tid & 63, w = tid >> 6;
    int wm = w >> 1, wn = w & 1;
    int row0 = blockIdx.x * TM, col0 = blockIdx.y * TN;

    f32x4 zf = {0.f, 0.f, 0.f, 0.f};
    f32x4 acc[4][4];
#pragma unroll
    for (int m = 0; m < 4; ++m)
#pragma unroll
        for (int n = 0; n < 4; ++n) acc[m][n] = zf;

    int srow = tid >> 2;
    int skoff = (tid & 3) << 3;
    const unsigned short* gA0 = A + (size_t)(row0 + srow) * KK + skoff;
    const unsigned short* gA1 = A + (size_t)(row0 + srow + 64) * KK + skoff;
    const unsigned short* gB0 = W + (size_t)(col0 + srow) * KK + skoff;
    const unsigned short* gB1 = W + (size_t)(col0 + srow + 64) * KK + skoff;
    short* lA0 = sA + tid * 8;
    short* lA1 = sA + 2048 + tid * 8;
    short* lB0 = sB + tid * 8;
    short* lB1 = sB + 2048 + tid * 8;

    int fk = (lane >> 4) << 3;    // k-chunk 0,8,16,24
    int fr = lane & 15;           // row/col within fragment

    for (int kb = 0; kb < KK; kb += TBK) {
        gload16(gA0 + kb, lA0);
        gload16(gA1 + kb, lA1);
        gload16(gB0 + kb, lB0);
        gload16(gB1 + kb, lB1);
        __syncthreads();
        bf16x8 af[4], bg[4];
#pragma unroll
        for (int m = 0; m < 4; ++m)
            af[m] = *(const bf16x8*)&sA[(wm * 64 + m * 16 + fr) * TBK + fk];
#pragma unroll
        for (int n = 0; n < 4; ++n)
            bg[n] = *(const bf16x8*)&sB[(wn * 64 + n * 16 + fr) * TBK + fk];
#pragma unroll
        for (int m = 0; m < 4; ++m)
#pragma unroll
            for (int n = 0; n < 4; ++n)
                acc[m][n] = __builtin_amdgcn_mfma_f32_16x16x32_bf16(af[m], bg[n], acc[m][n], 0, 0, 0);
        __syncthreads();
    }

    int crg = (lane >> 4) << 2;   // row=(lane>>4)*4+reg, col=lane&15
#pragma unroll
    for (int m = 0; m < 4; ++m) {
#pragma unroll
        for (int n = 0; n < 4; ++n) {
            int col = col0 + wn * 64 + n * 16 + fr;
            float bv = bias[col];
            int rowb = row0 + wm * 64 + m * 16 + crg;
#pragma unroll
            for (int r = 0; r < 4; ++r)
                C[(size_t)(rowb + r) * N + col] = acc[m][n][r] + bv;
        }
    }
}

// ---------------------------------------------------------------- attention (conflict-free, wave softmax)
__global__ __launch_bounds__(256)
void k_attn(const float* __restrict__ qkv,   // [B][65][1536]
            const float* __restrict__ biasb, // [B][16][65][65]
            unsigned short* __restrict__ o2) // [B*65][1024] hi|lo
{
    int h = blockIdx.x, b = blockIdx.y;
    int tid = threadIdx.x;
    int lane = tid & 63, w = tid >> 6;
    __shared__ float qT[HDD][NTOK + 1];   // [32][66] stride 66 -> 2-way (free)
    __shared__ float kT[HDD][NTOK + 1];
    __shared__ float sv[NTOK][HDD];       // [65][32]  lane d -> bank d
    __shared__ float sP[NTOK][NTOK + 1];  // [65][66]

    const float scale = 0.17677669529663687f;   // 1/sqrt(32)
    const float* qb = qkv + (size_t)b * NTOK * (3 * DD) + h * HDD;
    for (int i = tid; i < NTOK * HDD; i += 256) {
        int n = i >> 5, d = i & 31;
        const float* row = qb + (size_t)n * (3 * DD);
        qT[d][n] = row[d] * scale;
        kT[d][n] = row[DD + d];
        sv[n][d] = row[2 * DD + d];
    }
    __syncthreads();

    // fused scores + softmax: wave w owns rows w, w+4, w+8, ...
    const float* bp = biasb + (((size_t)b * HH + h) * NTOK) * NTOK;
    for (int i = w; i < NTOK; i += 4) {
        float s = 0.f;
#pragma unroll 8
        for (int d = 0; d < HDD; ++d)
            s += qT[d][i] * kT[d][lane];            // qT broadcast, kT 2-way free
        float s64p = (lane < HDD) ? qT[lane][i] * kT[lane][NTOK - 1] : 0.f;
#pragma unroll
        for (int off = 1; off < 64; off <<= 1) s64p += __shfl_xor(s64p, off);
        s += bp[i * NTOK + lane];
        float s64 = s64p + bp[i * NTOK + 64];
        float mx = s;
#pragma unroll
        for (int off = 1; off < 64; off <<= 1) mx = fmaxf(mx, __shfl_xor(mx, off));
        mx = fmaxf(mx, s64);
        float p = expf(s - mx);
        float p64 = expf(s64 - mx);
        float sum = p;
#pragma unroll
        for (int off = 1; off < 64; off <<= 1) sum += __shfl_xor(sum, off);
        sum += p64;
        float inv = 1.f / sum;
        sP[i][lane] = p * inv;
        if (lane == 0) sP[i][64] = p64 * inv;
    }
    __syncthreads();

    // PV: lane = half*32 + d; two rows per wave-iteration
    unsigned short* ob = o2 + (size_t)b * NTOK * KK2 + h * HDD;
    int half = lane >> 5, d = lane & 31;
    for (int ii = w; ii < NTOK; ii += 8) {
        int row = ii + half * 4;
        bool valid = row < NTOK;
        int rr = valid ? row : ii;
        float acc = 0.f;
#pragma unroll 5
        for (int j = 0; j < NTOK; ++j)
            acc += sP[rr][j] * sv[j][d];            // sP broadcast, sv conflict-free
        if (valid) {
            unsigned short hi = f2b_rne(acc);
            ob[(size_t)row * KK2 + d] = hi;
            ob[(size_t)row * KK2 + 512 + d] = f2b_rne(acc - b2f(hi));
        }
    }
}

// ---------------------------------------------------------------- launch
extern "C" void kernel_launch(void* const* d_in, const int* in_sizes, int n_in,
                              void* d_out, int out_size, void* d_ws, size_t ws_size,
                              hipStream_t stream)
{
    (void)in_sizes; (void)n_in; (void)out_size; (void)ws_size;
    const int*   atom_fea    = (const int*)d_in[0];
    const int*   bond_adj    = (const int*)d_in[1];
    const float* dist_adj    = (const float*)d_in[2];
    const float* atom_tables = (const float*)d_in[3];
    const float* ga_means    = (const float*)d_in[4];
    const float* ga_stds     = (const float*)d_in[5];
    const float* ga_mul      = (const float*)d_in[6];
    const float* ga_bias     = (const float*)d_in[7];
    const float* graph_token = (const float*)d_in[8];
    const float* edge_tables = (const float*)d_in[9];
    const float* gb_means    = (const float*)d_in[10];
    const float* gb_stds     = (const float*)d_in[11];
    const float* gb_mul      = (const float*)d_in[12];
    const float* gb_bias     = (const float*)d_in[13];
    const float* egt         = (const float*)d_in[14];
    const float* in_proj_w   = (const float*)d_in[15];
    const float* in_proj_b   = (const float*)d_in[16];
    const float* out_proj_w  = (const float*)d_in[17];
    const float* out_proj_b  = (const float*)d_in[18];

    const size_t MROWS = (size_t)BB * NTOK;                   // 16640
    char* base = (char*)d_ws;
    unsigned short* x2  = (unsigned short*)base;              // 34.1 MB [16640][1024] (reused as o2)
    float* qkv   = (float*)(base + MROWS * KK2 * 2);          // 102.2 MB [16640][1536]
    float* biasb = (float*)(base + MROWS * KK2 * 2 + MROWS * 3 * DD * 4);      // 69.2 MB
    unsigned short* wq2 = (unsigned short*)((char*)biasb + (size_t)BB * HH * NTOK * NTOK * 4); // 3.1 MB
    unsigned short* wo2 = wq2 + (size_t)3 * DD * KK2;         // 1.05 MB

    k_cvt_wdup<<<dim3((3 * DD * DD + 255) / 256), 256, 0, stream>>>(in_proj_w, wq2, 3 * DD * DD);
    k_cvt_wdup<<<dim3((DD * DD + 255) / 256), 256, 0, stream>>>(out_proj_w, wo2, DD * DD);
    k_atom_embed<<<dim3(NTOK, BB), 256, 0, stream>>>(atom_fea, atom_tables, ga_means,
                                                     ga_stds, ga_mul, ga_bias, graph_token, x2);
    k_edge_bias<<<dim3(BB), 1024, 0, stream>>>(bond_adj, dist_adj, edge_tables, gb_means,
                                               gb_stds, gb_mul, gb_bias, egt, biasb);
    k_gemm_mfma<<<dim3(130, 12), 256, 0, stream>>>(x2, wq2, in_proj_b, qkv,
                                                   (int)MROWS, 3 * DD, KK2);
    k_attn<<<dim3(HH, BB), 256, 0, stream>>>(qkv, biasb, x2 /* reused as o2 */);
    k_gemm_mfma<<<dim3(130, 4), 256, 0, stream>>>(x2, wo2, out_proj_b, (float*)d_out,
                                                  (int)MROWS, DD, KK2);
}

// Round 7
// 518.201 us; speedup vs baseline: 1.1326x; 1.1326x over previous
//
#include <hip/hip_runtime.h>
#include <math.h>

#define BB 256
#define NAA 64
#define NTOK 65
#define DD 512
#define KK2 1024          // split-A doubled K
#define HH 16
#define HDD 32
#define NGEFF 4           // bond values 0..15 -> bits 4,5 of (bond-1) always 0; table row 0 is 0
#define MAXP 50

typedef short bf16x8 __attribute__((ext_vector_type(8)));
typedef float f32x4 __attribute__((ext_vector_type(4)));

static __device__ __forceinline__ unsigned short f2b_rne(float f) {
    unsigned u = __float_as_uint(f);
    unsigned r = (u + 0x7FFFu + ((u >> 16) & 1u)) >> 16;
    return (unsigned short)r;
}
static __device__ __forceinline__ float b2f(unsigned short u) {
    return __uint_as_float(((unsigned)u) << 16);
}
static __device__ __forceinline__ void gload16(const void* g, void* l) {
    __builtin_amdgcn_global_load_lds(
        (const __attribute__((address_space(1))) unsigned int*)g,
        (__attribute__((address_space(3))) unsigned int*)l, 16, 0, 0);
}

// ---------------------------------------------------------------- weight convert+duplicate
__global__ __launch_bounds__(256)
void k_cvt_wdup(const float* __restrict__ w, unsigned short* __restrict__ w2, int n)
{
    int i = blockIdx.x * 256 + threadIdx.x;
    if (i >= n) return;
    int row = i >> 9, k = i & 511;
    unsigned short v = f2b_rne(w[i]);
    w2[(size_t)row * KK2 + k] = v;
    w2[(size_t)row * KK2 + k + 512] = v;
}

// ---------------------------------------------------------------- atom embed -> split bf16
__global__ __launch_bounds__(256)
void k_atom_embed(const int* __restrict__ atom_fea,          // [B][7][64]
                  const float* __restrict__ atom_tables,     // [6][100][512]
                  const float* __restrict__ ga_means,        // [512]
                  const float* __restrict__ ga_stds,
                  const float* __restrict__ ga_mul,
                  const float* __restrict__ ga_bias,
                  const float* __restrict__ graph_token,     // [512]
                  unsigned short* __restrict__ x2)           // [B*65][1024] hi|lo
{
    int n = blockIdx.x;   // 0..64
    int b = blockIdx.y;
    int tid = threadIdx.x;
    unsigned short* xp = x2 + ((size_t)b * NTOK + n) * KK2;
    if (n == 0) {
        for (int d = tid; d < DD; d += 256) {
            float val = graph_token[d];
            unsigned short h = f2b_rne(val);
            xp[d] = h;
            xp[d + 512] = f2b_rne(val - b2f(h));
        }
        return;
    }
    int a = n - 1;
    int fea[6];
#pragma unroll
    for (int i = 0; i < 6; ++i) fea[i] = atom_fea[((b * 7) + i) * NAA + a];
    int ci = atom_fea[((b * 7) + 6) * NAA + a];
    float cont = (float)ci;
    float g = ga_mul[0] * cont + ga_bias[0];
    const float Ac = 2.5066268f;    // sqrt(2*3.14159)
    for (int d = tid; d < DD; d += 256) {
        float val = 0.f;
        if (ci != 0) {
            float sd = fabsf(ga_stds[d]) + 1e-5f;
            float t = (g - ga_means[d]) / sd;
            val = expf(-0.5f * t * t) / (Ac * sd);
        }
#pragma unroll
        for (int i = 0; i < 6; ++i)
            val += atom_tables[((i * 100) + fea[i]) * DD + d];
        unsigned short h = f2b_rne(val);
        xp[d] = h;
        xp[d + 512] = f2b_rne(val - b2f(h));
    }
}

// ---------------------------------------------------------------- edge bias (fully LDS-resident)
__global__ __launch_bounds__(1024)
void k_edge_bias(const int* __restrict__ bond_adj,           // [B][64][64]
                 const float* __restrict__ dist_adj,         // [B][64][64]
                 const float* __restrict__ edge_tables,      // [6][51][16]
                 const float* __restrict__ gb_means,         // [16]
                 const float* __restrict__ gb_stds,
                 const float* __restrict__ gb_mul,
                 const float* __restrict__ gb_bias,
                 const float* __restrict__ egt,              // [16]
                 float* __restrict__ biasb)                  // [B][16][65][65]
{
    int b = blockIdx.x;
    int tid = threadIdx.x;
    __shared__ float s_j[64 * 65];
    __shared__ float s_jn[64 * 65];
    __shared__ unsigned long long s_brow[64];
    __shared__ unsigned char s_idx[16][4096];      // [t*4+hop][p]
    __shared__ float s_et[4][51][17];
    __shared__ int s_bond[4096];
    __shared__ float s_gmn[16], s_gis[16], s_gcf[16], s_egt[16];

    const int* badj = bond_adj + (size_t)b * 4096;
    const float Ac = 2.5066268f;

    for (int q = tid; q < 4096; q += 1024) s_bond[q] = badj[q];
    for (int q = tid; q < 4 * 51 * 16; q += 1024) {
        int t = q >> 4;
        int hh = q & 15;
        s_et[t / 51][t % 51][hh] = edge_tables[q];
    }
    if (tid < 16) {
        float sd = fabsf(gb_stds[tid]) + 1e-5f;
        s_gmn[tid] = gb_means[tid];
        s_gis[tid] = 1.f / sd;
        s_gcf[tid] = 1.f / (Ac * sd);
        s_egt[tid] = egt[tid];
    }
    __syncthreads();

    for (int t = 0; t < NGEFF; ++t) {
        for (int q = tid; q < 4096; q += 1024) {
            int bd = s_bond[q];
            int bit = (bd > 0) ? ((bd - 1) >> t) & 1 : 0;
            unsigned long long m = __ballot(bit != 0);
            if ((q & 63) == 0) s_brow[q >> 6] = m;
            s_j[(q >> 6) * 65 + (q & 63)] = (float)bit;
            s_idx[t * 4][q] = (unsigned char)bit;
        }
        __syncthreads();
        float* cur = s_j;
        float* nxt = s_jn;
        for (int hop = 1; hop < 4; ++hop) {
            int r = tid >> 4;
            int c0 = (tid & 15) << 2;
            float a0 = 0.f, a1 = 0.f, a2 = 0.f, a3 = 0.f;
            for (int k = 0; k < 64; ++k) {
                float jv = cur[r * 65 + k];
                unsigned int rs = (unsigned int)(s_brow[k] >> c0);
                a0 += (rs & 1u) ? jv : 0.f;
                a1 += (rs & 2u) ? jv : 0.f;
                a2 += (rs & 4u) ? jv : 0.f;
                a3 += (rs & 8u) ? jv : 0.f;
            }
            nxt[r * 65 + c0 + 0] = a0;
            nxt[r * 65 + c0 + 1] = a1;
            nxt[r * 65 + c0 + 2] = a2;
            nxt[r * 65 + c0 + 3] = a3;
            int p0 = r * 64 + c0;
            int i0 = (int)a0; if (i0 > MAXP) i0 = MAXP;
            int i1 = (int)a1; if (i1 > MAXP) i1 = MAXP;
            int i2 = (int)a2; if (i2 > MAXP) i2 = MAXP;
            int i3 = (int)a3; if (i3 > MAXP) i3 = MAXP;
            s_idx[t * 4 + hop][p0 + 0] = (unsigned char)i0;
            s_idx[t * 4 + hop][p0 + 1] = (unsigned char)i1;
            s_idx[t * 4 + hop][p0 + 2] = (unsigned char)i2;
            s_idx[t * 4 + hop][p0 + 3] = (unsigned char)i3;
            __syncthreads();
            float* tmp = cur; cur = nxt; nxt = tmp;
        }
    }

    float* bb = biasb + (size_t)b * HH * NTOK * NTOK;
    for (int i = tid; i < HH * NTOK; i += 1024) {
        int hh = i / NTOK, j = i - hh * NTOK;
        float e = s_egt[hh];
        bb[(hh * NTOK + 0) * NTOK + j] = e;
        bb[(hh * NTOK + j) * NTOK + 0] = e;
    }
    float gm = gb_mul[0], gbi = gb_bias[0];
    for (int p = tid; p < 4096; p += 1024) {
        int a1i = p >> 6, a2i = p & 63;
        float dist = dist_adj[(size_t)b * 4096 + p];
        float g = gm * dist + gbi;
        float mv = (s_bond[p] != 0) ? 0.f : -INFINITY;
        int ixs[16];
#pragma unroll
        for (int q = 0; q < 16; ++q) ixs[q] = s_idx[q][p];
#pragma unroll
        for (int hh = 0; hh < 16; ++hh) {
            float v = 0.f;
            if (dist != 0.f) {
                float tt = (g - s_gmn[hh]) * s_gis[hh];
                v = expf(-0.5f * tt * tt) * s_gcf[hh];
            }
#pragma unroll
            for (int q = 0; q < 16; ++q) v += s_et[q >> 2][ixs[q]][hh];
            bb[(hh * NTOK + a1i + 1) * NTOK + (a2i + 1)] = v + mv;
        }
    }
}

// ---------------------------------------------------------------- MFMA GEMM
#define TM 128
#define TN 128
#define TBK 32
__global__ __launch_bounds__(256)
void k_gemm_mfma(const unsigned short* __restrict__ A,
                 const unsigned short* __restrict__ W,
                 const float* __restrict__ bias,
                 float* __restrict__ C,
                 int M, int N, int KK)
{
    __shared__ short sA[TM * TBK];   // 8 KB
    __shared__ short sB[TN * TBK];   // 8 KB
    int tid = threadIdx.x;
    int lane = tid & 63, w = tid >> 6;
    int wm = w >> 1, wn = w & 1;
    int row0 = blockIdx.x * TM, col0 = blockIdx.y * TN;

    f32x4 zf = {0.f, 0.f, 0.f, 0.f};
    f32x4 acc[4][4];
#pragma unroll
    for (int m = 0; m < 4; ++m)
#pragma unroll
        for (int n = 0; n < 4; ++n) acc[m][n] = zf;

    int srow = tid >> 2;
    int skoff = (tid & 3) << 3;
    const unsigned short* gA0 = A + (size_t)(row0 + srow) * KK + skoff;
    const unsigned short* gA1 = A + (size_t)(row0 + srow + 64) * KK + skoff;
    const unsigned short* gB0 = W + (size_t)(col0 + srow) * KK + skoff;
    const unsigned short* gB1 = W + (size_t)(col0 + srow + 64) * KK + skoff;
    short* lA0 = sA + tid * 8;
    short* lA1 = sA + 2048 + tid * 8;
    short* lB0 = sB + tid * 8;
    short* lB1 = sB + 2048 + tid * 8;

    int fk = (lane >> 4) << 3;    // k-chunk 0,8,16,24
    int fr = lane & 15;           // row/col within fragment

    for (int kb = 0; kb < KK; kb += TBK) {
        gload16(gA0 + kb, lA0);
        gload16(gA1 + kb, lA1);
        gload16(gB0 + kb, lB0);
        gload16(gB1 + kb, lB1);
        __syncthreads();
        bf16x8 af[4], bg[4];
#pragma unroll
        for (int m = 0; m < 4; ++m)
            af[m] = *(const bf16x8*)&sA[(wm * 64 + m * 16 + fr) * TBK + fk];
#pragma unroll
        for (int n = 0; n < 4; ++n)
            bg[n] = *(const bf16x8*)&sB[(wn * 64 + n * 16 + fr) * TBK + fk];
#pragma unroll
        for (int m = 0; m < 4; ++m)
#pragma unroll
            for (int n = 0; n < 4; ++n)
                acc[m][n] = __builtin_amdgcn_mfma_f32_16x16x32_bf16(af[m], bg[n], acc[m][n], 0, 0, 0);
        __syncthreads();
    }

    int crg = (lane >> 4) << 2;   // row=(lane>>4)*4+reg, col=lane&15
#pragma unroll
    for (int m = 0; m < 4; ++m) {
#pragma unroll
        for (int n = 0; n < 4; ++n) {
            int col = col0 + wn * 64 + n * 16 + fr;
            float bv = bias[col];
            int rowb = row0 + wm * 64 + m * 16 + crg;
#pragma unroll
            for (int r = 0; r < 4; ++r)
                C[(size_t)(rowb + r) * N + col] = acc[m][n][r] + bv;
        }
    }
}

// ---------------------------------------------------------------- attention via MFMA (hi/lo split)
__global__ __launch_bounds__(256)
void k_attn(const float* __restrict__ qkv,   // [B][65][1536]
            const float* __restrict__ biasb, // [B][16][65][65]
            unsigned short* __restrict__ o2) // [B*65][1024] hi|lo
{
    int h = blockIdx.x, b = blockIdx.y;
    int tid = threadIdx.x;
    int lane = tid & 63, w = tid >> 6;
    __shared__ unsigned short Qh[80 * 32], Ql[80 * 32];   // 5 KB each (rows 65-79 zero)
    __shared__ unsigned short Kh[80 * 32], Kl[80 * 32];
    __shared__ unsigned short Vh[32 * 96], Vl[32 * 96];   // V^T [d][n], cols 65-95 zero
    __shared__ float SP[80 * 96];                         // S f32; later P hi|lo ushorts

    const float scale = 0.17677669529663687f;   // 1/sqrt(32)
    const float* qb = qkv + (size_t)b * NTOK * (3 * DD) + h * HDD;

    // load + hi/lo split (scale folded into Q)
    for (int i = tid; i < NTOK * HDD; i += 256) {
        int n = i >> 5, d = i & 31;
        const float* row = qb + (size_t)n * (3 * DD);
        float q = row[d] * scale, k = row[DD + d], v = row[2 * DD + d];
        unsigned short qh = f2b_rne(q);
        Qh[n * 32 + d] = qh; Ql[n * 32 + d] = f2b_rne(q - b2f(qh));
        unsigned short kh = f2b_rne(k);
        Kh[n * 32 + d] = kh; Kl[n * 32 + d] = f2b_rne(k - b2f(kh));
        unsigned short vh = f2b_rne(v);
        Vh[d * 96 + n] = vh; Vl[d * 96 + n] = f2b_rne(v - b2f(vh));
    }
    for (int i = tid; i < 15 * 32; i += 256) {      // zero-pad Q/K rows 65..79
        int n = 65 + (i >> 5), d = i & 31;
        Qh[n * 32 + d] = 0; Ql[n * 32 + d] = 0;
        Kh[n * 32 + d] = 0; Kl[n * 32 + d] = 0;
    }
    for (int i = tid; i < 32 * 31; i += 256) {      // zero-pad V^T cols 65..95
        int d = i / 31, n = 65 + i % 31;
        Vh[d * 96 + n] = 0; Vl[d * 96 + n] = 0;
    }
    __syncthreads();

    int fr = lane & 15, fc = lane >> 4;
    // scores: 25 tiles of 16x16, 3 MFMAs each (QhKh + QhKl + QlKh)
    const float* bp = biasb + (((size_t)b * HH + h) * NTOK) * NTOK;
    for (int t = w; t < 25; t += 4) {
        int rt = t / 5, ct = t % 5;
        bf16x8 aQh = *(const bf16x8*)&Qh[(rt * 16 + fr) * 32 + fc * 8];
        bf16x8 aQl = *(const bf16x8*)&Ql[(rt * 16 + fr) * 32 + fc * 8];
        bf16x8 bKh = *(const bf16x8*)&Kh[(ct * 16 + fr) * 32 + fc * 8];
        bf16x8 bKl = *(const bf16x8*)&Kl[(ct * 16 + fr) * 32 + fc * 8];
        f32x4 acc = {0.f, 0.f, 0.f, 0.f};
        acc = __builtin_amdgcn_mfma_f32_16x16x32_bf16(aQh, bKh, acc, 0, 0, 0);
        acc = __builtin_amdgcn_mfma_f32_16x16x32_bf16(aQh, bKl, acc, 0, 0, 0);
        acc = __builtin_amdgcn_mfma_f32_16x16x32_bf16(aQl, bKh, acc, 0, 0, 0);
        int col = ct * 16 + fr;
#pragma unroll
        for (int r = 0; r < 4; ++r) {
            int row = rt * 16 + fc * 4 + r;
            float sv = 0.f;
            if (row < 65 && col < 65) sv = acc[r] + bp[row * NTOK + col];
            SP[row * 96 + col] = sv;
        }
    }
    __syncthreads();

    // softmax: 16-lane groups, 4 rows per wave per sweep
    int g = fc, c16 = fr;
    for (int sweep = 0; sweep < 5; ++sweep) {
        int i = sweep * 16 + w * 4 + g;
        if (i < 65) {
            float pv[5];
            float mx = -INFINITY;
#pragma unroll
            for (int q = 0; q < 5; ++q) {
                int c = c16 + q * 16;
                pv[q] = (c < 65) ? SP[i * 96 + c] : -INFINITY;
                mx = fmaxf(mx, pv[q]);
            }
#pragma unroll
            for (int off = 1; off < 16; off <<= 1) mx = fmaxf(mx, __shfl_xor(mx, off));
            float sum = 0.f;
#pragma unroll
            for (int q = 0; q < 5; ++q) { pv[q] = expf(pv[q] - mx); sum += pv[q]; }
#pragma unroll
            for (int off = 1; off < 16; off <<= 1) sum += __shfl_xor(sum, off);
            float inv = 1.f / sum;
#pragma unroll
            for (int q = 0; q < 5; ++q) {
                int c = c16 + q * 16;
                if (c < 65) SP[i * 96 + c] = pv[q] * inv;
            }
        }
    }
    __syncthreads();

    // P -> hi/lo bf16 in place (register-staged across a barrier)
    float pr[30];
#pragma unroll
    for (int k2 = 0; k2 < 30; ++k2) {
        int idx = k2 * 256 + tid;
        int row = idx / 96, j = idx - row * 96;
        pr[k2] = (row < 65 && j < 65) ? SP[row * 96 + j] : 0.f;
    }
    __syncthreads();
    unsigned short* SPu = (unsigned short*)SP;
#pragma unroll
    for (int k2 = 0; k2 < 30; ++k2) {
        int idx = k2 * 256 + tid;
        int row = idx / 96, j = idx - row * 96;
        unsigned short hi = f2b_rne(pr[k2]);
        SPu[row * 192 + j] = hi;
        SPu[row * 192 + 96 + j] = f2b_rne(pr[k2] - b2f(hi));
    }
    __syncthreads();

    // PV: 10 tiles (5 row x 2 col), K=96 in 3 chunks, 3 MFMAs each (PhVh+PhVl+PlVh)
    unsigned short* ob = o2 + (size_t)b * NTOK * KK2 + h * HDD;
    for (int t = w; t < 10; t += 4) {
        int rt = t / 2, ct = t % 2;
        f32x4 acc = {0.f, 0.f, 0.f, 0.f};
#pragma unroll
        for (int kc = 0; kc < 3; ++kc) {
            bf16x8 aPh = *(const bf16x8*)&SPu[(rt * 16 + fr) * 192 + kc * 32 + fc * 8];
            bf16x8 aPl = *(const bf16x8*)&SPu[(rt * 16 + fr) * 192 + 96 + kc * 32 + fc * 8];
            bf16x8 bVh = *(const bf16x8*)&Vh[(ct * 16 + fr) * 96 + kc * 32 + fc * 8];
            bf16x8 bVl = *(const bf16x8*)&Vl[(ct * 16 + fr) * 96 + kc * 32 + fc * 8];
            acc = __builtin_amdgcn_mfma_f32_16x16x32_bf16(aPh, bVh, acc, 0, 0, 0);
            acc = __builtin_amdgcn_mfma_f32_16x16x32_bf16(aPh, bVl, acc, 0, 0, 0);
            acc = __builtin_amdgcn_mfma_f32_16x16x32_bf16(aPl, bVh, acc, 0, 0, 0);
        }
        int d = ct * 16 + fr;
#pragma unroll
        for (int r = 0; r < 4; ++r) {
            int row = rt * 16 + fc * 4 + r;
            if (row < 65) {
                unsigned short hi = f2b_rne(acc[r]);
                ob[(size_t)row * KK2 + d] = hi;
                ob[(size_t)row * KK2 + 512 + d] = f2b_rne(acc[r] - b2f(hi));
            }
        }
    }
}

// ---------------------------------------------------------------- launch
extern "C" void kernel_launch(void* const* d_in, const int* in_sizes, int n_in,
                              void* d_out, int out_size, void* d_ws, size_t ws_size,
                              hipStream_t stream)
{
    (void)in_sizes; (void)n_in; (void)out_size; (void)ws_size;
    const int*   atom_fea    = (const int*)d_in[0];
    const int*   bond_adj    = (const int*)d_in[1];
    const float* dist_adj    = (const float*)d_in[2];
    const float* atom_tables = (const float*)d_in[3];
    const float* ga_means    = (const float*)d_in[4];
    const float* ga_stds     = (const float*)d_in[5];
    const float* ga_mul      = (const float*)d_in[6];
    const float* ga_bias     = (const float*)d_in[7];
    const float* graph_token = (const float*)d_in[8];
    const float* edge_tables = (const float*)d_in[9];
    const float* gb_means    = (const float*)d_in[10];
    const float* gb_stds     = (const float*)d_in[11];
    const float* gb_mul      = (const float*)d_in[12];
    const float* gb_bias     = (const float*)d_in[13];
    const float* egt         = (const float*)d_in[14];
    const float* in_proj_w   = (const float*)d_in[15];
    const float* in_proj_b   = (const float*)d_in[16];
    const float* out_proj_w  = (const float*)d_in[17];
    const float* out_proj_b  = (const float*)d_in[18];

    const size_t MROWS = (size_t)BB * NTOK;                   // 16640
    char* base = (char*)d_ws;
    unsigned short* x2  = (unsigned short*)base;              // 34.1 MB [16640][1024] (reused as o2)
    float* qkv   = (float*)(base + MROWS * KK2 * 2);          // 102.2 MB [16640][1536]
    float* biasb = (float*)(base + MROWS * KK2 * 2 + MROWS * 3 * DD * 4);      // 69.2 MB
    unsigned short* wq2 = (unsigned short*)((char*)biasb + (size_t)BB * HH * NTOK * NTOK * 4); // 3.1 MB
    unsigned short* wo2 = wq2 + (size_t)3 * DD * KK2;         // 1.05 MB

    k_cvt_wdup<<<dim3((3 * DD * DD + 255) / 256), 256, 0, stream>>>(in_proj_w, wq2, 3 * DD * DD);
    k_cvt_wdup<<<dim3((DD * DD + 255) / 256), 256, 0, stream>>>(out_proj_w, wo2, DD * DD);
    k_atom_embed<<<dim3(NTOK, BB), 256, 0, stream>>>(atom_fea, atom_tables, ga_means,
                                                     ga_stds, ga_mul, ga_bias, graph_token, x2);
    k_edge_bias<<<dim3(BB), 1024, 0, stream>>>(bond_adj, dist_adj, edge_tables, gb_means,
                                               gb_stds, gb_mul, gb_bias, egt, biasb);
    k_gemm_mfma<<<dim3(130, 12), 256, 0, stream>>>(x2, wq2, in_proj_b, qkv,
                                                   (int)MROWS, 3 * DD, KK2);
    k_attn<<<dim3(HH, BB), 256, 0, stream>>>(qkv, biasb, x2 /* reused as o2 */);
    k_gemm_mfma<<<dim3(130, 4), 256, 0, stream>>>(x2, wo2, out_proj_b, (float*)d_out,
                                                  (int)MROWS, DD, KK2);
}

// Round 11
// 492.086 us; speedup vs baseline: 1.1927x; 1.0531x over previous
//
#include <hip/hip_runtime.h>
#include <math.h>

#define BB 256
#define NAA 64
#define NTOK 65
#define DD 512
#define KK2 1024          // split-A doubled K (qkv projection)
#define HH 16
#define HDD 32
#define NGEFF 4           // bond values 0..15 -> bits 4,5 of (bond-1) always 0; table row 0 is 0
#define MAXP 50

typedef short bf16x8 __attribute__((ext_vector_type(8)));
typedef float f32x4 __attribute__((ext_vector_type(4)));

static __device__ __forceinline__ unsigned short f2b_rne(float f) {
    unsigned u = __float_as_uint(f);
    unsigned r = (u + 0x7FFFu + ((u >> 16) & 1u)) >> 16;
    return (unsigned short)r;
}
static __device__ __forceinline__ float b2f(unsigned short u) {
    return __uint_as_float(((unsigned)u) << 16);
}
static __device__ __forceinline__ void gload16(const void* g, void* l) {
    __builtin_amdgcn_global_load_lds(
        (const __attribute__((address_space(1))) unsigned int*)g,
        (__attribute__((address_space(3))) unsigned int*)l, 16, 0, 0);
}

// ---------------------------------------------------------------- weight converts
__global__ __launch_bounds__(256)
void k_cvt_wdup(const float* __restrict__ w, unsigned short* __restrict__ w2, int n)
{
    int i = blockIdx.x * 256 + threadIdx.x;
    if (i >= n) return;
    int row = i >> 9, k = i & 511;
    unsigned short v = f2b_rne(w[i]);
    w2[(size_t)row * KK2 + k] = v;
    w2[(size_t)row * KK2 + k + 512] = v;
}
__global__ __launch_bounds__(256)
void k_cvt_w(const float* __restrict__ w, unsigned short* __restrict__ w2, int n)
{
    int i = blockIdx.x * 256 + threadIdx.x;
    if (i >= n) return;
    w2[i] = f2b_rne(w[i]);
}

// ---------------------------------------------------------------- atom embed -> split bf16
__global__ __launch_bounds__(256)
void k_atom_embed(const int* __restrict__ atom_fea,          // [B][7][64]
                  const float* __restrict__ atom_tables,     // [6][100][512]
                  const float* __restrict__ ga_means,        // [512]
                  const float* __restrict__ ga_stds,
                  const float* __restrict__ ga_mul,
                  const float* __restrict__ ga_bias,
                  const float* __restrict__ graph_token,     // [512]
                  unsigned short* __restrict__ x2)           // [B*65][1024] hi|lo
{
    int n = blockIdx.x;   // 0..64
    int b = blockIdx.y;
    int tid = threadIdx.x;
    unsigned short* xp = x2 + ((size_t)b * NTOK + n) * KK2;
    if (n == 0) {
        for (int d = tid; d < DD; d += 256) {
            float val = graph_token[d];
            unsigned short h = f2b_rne(val);
            xp[d] = h;
            xp[d + 512] = f2b_rne(val - b2f(h));
        }
        return;
    }
    int a = n - 1;
    int fea[6];
#pragma unroll
    for (int i = 0; i < 6; ++i) fea[i] = atom_fea[((b * 7) + i) * NAA + a];
    int ci = atom_fea[((b * 7) + 6) * NAA + a];
    float cont = (float)ci;
    float g = ga_mul[0] * cont + ga_bias[0];
    const float Ac = 2.5066268f;    // sqrt(2*3.14159)
    for (int d = tid; d < DD; d += 256) {
        float val = 0.f;
        if (ci != 0) {
            float sd = fabsf(ga_stds[d]) + 1e-5f;
            float t = (g - ga_means[d]) / sd;
            val = expf(-0.5f * t * t) / (Ac * sd);
        }
#pragma unroll
        for (int i = 0; i < 6; ++i)
            val += atom_tables[((i * 100) + fea[i]) * DD + d];
        unsigned short h = f2b_rne(val);
        xp[d] = h;
        xp[d + 512] = f2b_rne(val - b2f(h));
    }
}

// ---------------------------------------------------------------- edge bias (fully LDS-resident)
__global__ __launch_bounds__(1024)
void k_edge_bias(const int* __restrict__ bond_adj,           // [B][64][64]
                 const float* __restrict__ dist_adj,         // [B][64][64]
                 const float* __restrict__ edge_tables,      // [6][51][16]
                 const float* __restrict__ gb_means,         // [16]
                 const float* __restrict__ gb_stds,
                 const float* __restrict__ gb_mul,
                 const float* __restrict__ gb_bias,
                 const float* __restrict__ egt,              // [16]
                 float* __restrict__ biasb)                  // [B][16][65][65]
{
    int b = blockIdx.x;
    int tid = threadIdx.x;
    __shared__ float s_j[64 * 65];
    __shared__ float s_jn[64 * 65];
    __shared__ unsigned long long s_brow[64];
    __shared__ unsigned char s_idx[16][4096];      // [t*4+hop][p]
    __shared__ float s_et[4][51][17];
    __shared__ int s_bond[4096];
    __shared__ float s_gmn[16], s_gis[16], s_gcf[16], s_egt[16];

    const int* badj = bond_adj + (size_t)b * 4096;
    const float Ac = 2.5066268f;

    for (int q = tid; q < 4096; q += 1024) s_bond[q] = badj[q];
    for (int q = tid; q < 4 * 51 * 16; q += 1024) {
        int t = q >> 4;
        int hh = q & 15;
        s_et[t / 51][t % 51][hh] = edge_tables[q];
    }
    if (tid < 16) {
        float sd = fabsf(gb_stds[tid]) + 1e-5f;
        s_gmn[tid] = gb_means[tid];
        s_gis[tid] = 1.f / sd;
        s_gcf[tid] = 1.f / (Ac * sd);
        s_egt[tid] = egt[tid];
    }
    __syncthreads();

    for (int t = 0; t < NGEFF; ++t) {
        for (int q = tid; q < 4096; q += 1024) {
            int bd = s_bond[q];
            int bit = (bd > 0) ? ((bd - 1) >> t) & 1 : 0;
            unsigned long long m = __ballot(bit != 0);
            if ((q & 63) == 0) s_brow[q >> 6] = m;
            s_j[(q >> 6) * 65 + (q & 63)] = (float)bit;
            s_idx[t * 4][q] = (unsigned char)bit;
        }
        __syncthreads();
        float* cur = s_j;
        float* nxt = s_jn;
        for (int hop = 1; hop < 4; ++hop) {
            int r = tid >> 4;
            int c0 = (tid & 15) << 2;
            float a0 = 0.f, a1 = 0.f, a2 = 0.f, a3 = 0.f;
            for (int k = 0; k < 64; ++k) {
                float jv = cur[r * 65 + k];
                unsigned int rs = (unsigned int)(s_brow[k] >> c0);
                a0 += (rs & 1u) ? jv : 0.f;
                a1 += (rs & 2u) ? jv : 0.f;
                a2 += (rs & 4u) ? jv : 0.f;
                a3 += (rs & 8u) ? jv : 0.f;
            }
            nxt[r * 65 + c0 + 0] = a0;
            nxt[r * 65 + c0 + 1] = a1;
            nxt[r * 65 + c0 + 2] = a2;
            nxt[r * 65 + c0 + 3] = a3;
            int p0 = r * 64 + c0;
            int i0 = (int)a0; if (i0 > MAXP) i0 = MAXP;
            int i1 = (int)a1; if (i1 > MAXP) i1 = MAXP;
            int i2 = (int)a2; if (i2 > MAXP) i2 = MAXP;
            int i3 = (int)a3; if (i3 > MAXP) i3 = MAXP;
            s_idx[t * 4 + hop][p0 + 0] = (unsigned char)i0;
            s_idx[t * 4 + hop][p0 + 1] = (unsigned char)i1;
            s_idx[t * 4 + hop][p0 + 2] = (unsigned char)i2;
            s_idx[t * 4 + hop][p0 + 3] = (unsigned char)i3;
            __syncthreads();
            float* tmp = cur; cur = nxt; nxt = tmp;
        }
    }

    float* bb = biasb + (size_t)b * HH * NTOK * NTOK;
    for (int i = tid; i < HH * NTOK; i += 1024) {
        int hh = i / NTOK, j = i - hh * NTOK;
        float e = s_egt[hh];
        bb[(hh * NTOK + 0) * NTOK + j] = e;
        bb[(hh * NTOK + j) * NTOK + 0] = e;
    }
    float gm = gb_mul[0], gbi = gb_bias[0];
    for (int p = tid; p < 4096; p += 1024) {
        int a1i = p >> 6, a2i = p & 63;
        float dist = dist_adj[(size_t)b * 4096 + p];
        float g = gm * dist + gbi;
        float mv = (s_bond[p] != 0) ? 0.f : -INFINITY;
        int ixs[16];
#pragma unroll
        for (int q = 0; q < 16; ++q) ixs[q] = s_idx[q][p];
#pragma unroll
        for (int hh = 0; hh < 16; ++hh) {
            float v = 0.f;
            if (dist != 0.f) {
                float tt = (g - s_gmn[hh]) * s_gis[hh];
                v = expf(-0.5f * tt * tt) * s_gcf[hh];
            }
#pragma unroll
            for (int q = 0; q < 16; ++q) v += s_et[q >> 2][ixs[q]][hh];
            bb[(hh * NTOK + a1i + 1) * NTOK + (a2i + 1)] = v + mv;
        }
    }
}

// ---------------------------------------------------------------- MFMA GEMM
#define TM 128
#define TN 128
#define TBK 32
__global__ __launch_bounds__(256)
void k_gemm_mfma(const unsigned short* __restrict__ A,
                 const unsigned short* __restrict__ W,
                 const float* __restrict__ bias,
                 float* __restrict__ C,
                 int M, int N, int KK)
{
    __shared__ short sA[TM * TBK];   // 8 KB
    __shared__ short sB[TN * TBK];   // 8 KB
    int tid = threadIdx.x;
    int lane = tid & 63, w = tid >> 6;
    int wm = w >> 1, wn = w & 1;
    int row0 = blockIdx.x * TM, col0 = blockIdx.y * TN;

    f32x4 zf = {0.f, 0.f, 0.f, 0.f};
    f32x4 acc[4][4];
#pragma unroll
    for (int m = 0; m < 4; ++m)
#pragma unroll
        for (int n = 0; n < 4; ++n) acc[m][n] = zf;

    int srow = tid >> 2;
    int skoff = (tid & 3) << 3;
    const unsigned short* gA0 = A + (size_t)(row0 + srow) * KK + skoff;
    const unsigned short* gA1 = A + (size_t)(row0 + srow + 64) * KK + skoff;
    const unsigned short* gB0 = W + (size_t)(col0 + srow) * KK + skoff;
    const unsigned short* gB1 = W + (size_t)(col0 + srow + 64) * KK + skoff;
    short* lA0 = sA + tid * 8;
    short* lA1 = sA + 2048 + tid * 8;
    short* lB0 = sB + tid * 8;
    short* lB1 = sB + 2048 + tid * 8;

    int fk = (lane >> 4) << 3;    // k-chunk 0,8,16,24
    int fr = lane & 15;           // row/col within fragment

    for (int kb = 0; kb < KK; kb += TBK) {
        gload16(gA0 + kb, lA0);
        gload16(gA1 + kb, lA1);
        gload16(gB0 + kb, lB0);
        gload16(gB1 + kb, lB1);
        __syncthreads();
        bf16x8 af[4], bg[4];
#pragma unroll
        for (int m = 0; m < 4; ++m)
            af[m] = *(const bf16x8*)&sA[(wm * 64 + m * 16 + fr) * TBK + fk];
#pragma unroll
        for (int n = 0; n < 4; ++n)
            bg[n] = *(const bf16x8*)&sB[(wn * 64 + n * 16 + fr) * TBK + fk];
#pragma unroll
        for (int m = 0; m < 4; ++m)
#pragma unroll
            for (int n = 0; n < 4; ++n)
                acc[m][n] = __builtin_amdgcn_mfma_f32_16x16x32_bf16(af[m], bg[n], acc[m][n], 0, 0, 0);
        __syncthreads();
    }

    int crg = (lane >> 4) << 2;   // row=(lane>>4)*4+reg, col=lane&15
#pragma unroll
    for (int m = 0; m < 4; ++m) {
#pragma unroll
        for (int n = 0; n < 4; ++n) {
            int col = col0 + wn * 64 + n * 16 + fr;
            float bv = bias[col];
            int rowb = row0 + wm * 64 + m * 16 + crg;
#pragma unroll
            for (int r = 0; r < 4; ++r)
                C[(size_t)(rowb + r) * N + col] = acc[m][n][r] + bv;
        }
    }
}

// ---------------------------------------------------------------- attention via MFMA, fragment-order LDS
// Layouts (u16 element indices):
//   Q/K  : QF(rt,fc,fr,j) = ((rt*4+fc)*16+fr)*8+j          (2560 u16)  read at rt*512 + lane*8
//   V^T  : VF(ct,kc,fc,fr,j) = ((ct*3+kc)*64 + fc*16+fr)*8+j (3072 u16) read at (ct*3+kc)*512 + lane*8
//   P    : PF(rt,hl,kc,lane,j) = ((rt*6+hl*3+kc)*64+lane)*8+j (15360 u16, aliased on SP)
//   SP f32: [80][100] (stride 100 spreads banks: row*100 % 32 = 4*row)
__global__ __launch_bounds__(256)
void k_attn(const float* __restrict__ qkv,   // [B][65][1536]
            const float* __restrict__ biasb, // [B][16][65][65]
            unsigned short* __restrict__ o2) // [B*65][512] bf16
{
    int h = blockIdx.x, b = blockIdx.y;
    int tid = threadIdx.x;
    int lane = tid & 63, w = tid >> 6;
    __shared__ unsigned short Qh[2560], Ql[2560];
    __shared__ unsigned short Kh[2560], Kl[2560];
    __shared__ unsigned short Vh[3072], Vl[3072];
    __shared__ float SP[80 * 100];                 // 32000 B; aliased as P frag (30720 B)

    const float scale = 0.17677669529663687f;   // 1/sqrt(32)
    const float* qb = qkv + (size_t)b * NTOK * (3 * DD) + h * HDD;

    // fill (fragment-order) + zero-pad tails
    for (int i = tid; i < NTOK * HDD; i += 256) {
        int n = i >> 5, d = i & 31;
        const float* row = qb + (size_t)n * (3 * DD);
        float q = row[d] * scale, k = row[DD + d], v = row[2 * DD + d];
        int qa = (((n >> 4) * 4 + (d >> 3)) * 16 + (n & 15)) * 8 + (d & 7);
        unsigned short qh = f2b_rne(q);
        Qh[qa] = qh; Ql[qa] = f2b_rne(q - b2f(qh));
        unsigned short kh = f2b_rne(k);
        Kh[qa] = kh; Kl[qa] = f2b_rne(k - b2f(kh));
        int va = ((((d >> 4) * 3 + (n >> 5)) * 4 + ((n & 31) >> 3)) * 16 + (d & 15)) * 8 + (n & 7);
        unsigned short vh = f2b_rne(v);
        Vh[va] = vh; Vl[va] = f2b_rne(v - b2f(vh));
    }
    for (int i = tid; i < 480; i += 256) {          // Q/K rows n=65..79
        int n = 65 + (i >> 5), d = i & 31;
        int qa = (((n >> 4) * 4 + (d >> 3)) * 16 + (n & 15)) * 8 + (d & 7);
        Qh[qa] = 0; Ql[qa] = 0; Kh[qa] = 0; Kl[qa] = 0;
    }
    for (int i = tid; i < 992; i += 256) {          // V cols n=65..95
        int n = 65 + (i >> 5), d = i & 31;
        int va = ((((d >> 4) * 3 + (n >> 5)) * 4 + ((n & 31) >> 3)) * 16 + (d & 15)) * 8 + (n & 7);
        Vh[va] = 0; Vl[va] = 0;
    }
    __syncthreads();

    int fr = lane & 15, fc = lane >> 4;
    // scores: 25 tiles, conflict-free lane-linear fragment reads
    const float* bp = biasb + (((size_t)b * HH + h) * NTOK) * NTOK;
    for (int t = w; t < 25; t += 4) {
        int rt = t / 5, ct = t % 5;
        bf16x8 aQh = *(const bf16x8*)&Qh[rt * 512 + lane * 8];
        bf16x8 aQl = *(const bf16x8*)&Ql[rt * 512 + lane * 8];
        bf16x8 bKh = *(const bf16x8*)&Kh[ct * 512 + lane * 8];
        bf16x8 bKl = *(const bf16x8*)&Kl[ct * 512 + lane * 8];
        f32x4 acc = {0.f, 0.f, 0.f, 0.f};
        acc = __builtin_amdgcn_mfma_f32_16x16x32_bf16(aQh, bKh, acc, 0, 0, 0);
        acc = __builtin_amdgcn_mfma_f32_16x16x32_bf16(aQh, bKl, acc, 0, 0, 0);
        acc = __builtin_amdgcn_mfma_f32_16x16x32_bf16(aQl, bKh, acc, 0, 0, 0);
        int col = ct * 16 + fr;
#pragma unroll
        for (int r = 0; r < 4; ++r) {
            int row = rt * 16 + fc * 4 + r;
            float sv = 0.f;
            if (row < 65 && col < 65) sv = acc[r] + bp[row * NTOK + col];
            SP[row * 100 + col] = sv;
        }
    }
    __syncthreads();

    // softmax: 16-lane groups, 4 rows per wave per sweep
    for (int sweep = 0; sweep < 5; ++sweep) {
        int i = sweep * 16 + w * 4 + fc;
        if (i < 65) {
            float pv[5];
            float mx = -INFINITY;
#pragma unroll
            for (int q = 0; q < 5; ++q) {
                int c = fr + q * 16;
                pv[q] = (c < 65) ? SP[i * 100 + c] : -INFINITY;
                mx = fmaxf(mx, pv[q]);
            }
#pragma unroll
            for (int off = 1; off < 16; off <<= 1) mx = fmaxf(mx, __shfl_xor(mx, off));
            float sum = 0.f;
#pragma unroll
            for (int q = 0; q < 5; ++q) { pv[q] = expf(pv[q] - mx); sum += pv[q]; }
#pragma unroll
            for (int off = 1; off < 16; off <<= 1) sum += __shfl_xor(sum, off);
            float inv = 1.f / sum;
#pragma unroll
            for (int q = 0; q < 5; ++q) {
                int c = fr + q * 16;
                if (c < 65) SP[i * 100 + c] = pv[q] * inv;
            }
        }
    }
    __syncthreads();

    // P -> hi/lo bf16 fragment-order, in place (register-staged)
    int cl = tid >> 3, cj = tid & 7;       // chunk-lane base, j within chunk
    float pr[30];
    {
        int cnt = 0;
#pragma unroll
        for (int rt = 0; rt < 5; ++rt)
#pragma unroll
            for (int kc = 0; kc < 3; ++kc)
#pragma unroll
                for (int s = 0; s < 2; ++s) {
                    int lane2 = cl + s * 32;
                    int row = rt * 16 + (lane2 & 15);
                    int col = kc * 32 + (lane2 >> 4) * 8 + cj;
                    pr[cnt++] = (row < 65 && col < 65) ? SP[row * 100 + col] : 0.f;
                }
    }
    __syncthreads();
    unsigned short* SPu = (unsigned short*)SP;
    {
        int cnt = 0;
#pragma unroll
        for (int rt = 0; rt < 5; ++rt)
#pragma unroll
            for (int kc = 0; kc < 3; ++kc)
#pragma unroll
                for (int s = 0; s < 2; ++s) {
                    int lane2 = cl + s * 32;
                    float p = pr[cnt++];
                    unsigned short hi = f2b_rne(p);
                    SPu[(rt * 6 + kc) * 512 + lane2 * 8 + cj] = hi;
                    SPu[(rt * 6 + 3 + kc) * 512 + lane2 * 8 + cj] = f2b_rne(p - b2f(hi));
                }
    }
    __syncthreads();

    // PV: 10 tiles (5 rt x 2 ct), K=96 in 3 chunks, conflict-free reads
    unsigned short* ob = o2 + ((size_t)b * NTOK) * DD + h * HDD;
    for (int t = w; t < 10; t += 4) {
        int rt = t >> 1, ct = t & 1;
        f32x4 acc = {0.f, 0.f, 0.f, 0.f};
#pragma unroll
        for (int kc = 0; kc < 3; ++kc) {
            bf16x8 aPh = *(const bf16x8*)&SPu[(rt * 6 + kc) * 512 + lane * 8];
            bf16x8 aPl = *(const bf16x8*)&SPu[(rt * 6 + 3 + kc) * 512 + lane * 8];
            bf16x8 bVh = *(const bf16x8*)&Vh[(ct * 3 + kc) * 512 + lane * 8];
            bf16x8 bVl = *(const bf16x8*)&Vl[(ct * 3 + kc) * 512 + lane * 8];
            acc = __builtin_amdgcn_mfma_f32_16x16x32_bf16(aPh, bVh, acc, 0, 0, 0);
            acc = __builtin_amdgcn_mfma_f32_16x16x32_bf16(aPh, bVl, acc, 0, 0, 0);
            acc = __builtin_amdgcn_mfma_f32_16x16x32_bf16(aPl, bVh, acc, 0, 0, 0);
        }
        int d = ct * 16 + fr;
#pragma unroll
        for (int r = 0; r < 4; ++r) {
            int row = rt * 16 + fc * 4 + r;
            if (row < 65)
                ob[(size_t)row * DD + d] = f2b_rne(acc[r]);
        }
    }
}

// ---------------------------------------------------------------- launch
extern "C" void kernel_launch(void* const* d_in, const int* in_sizes, int n_in,
                              void* d_out, int out_size, void* d_ws, size_t ws_size,
                              hipStream_t stream)
{
    (void)in_sizes; (void)n_in; (void)out_size; (void)ws_size;
    const int*   atom_fea    = (const int*)d_in[0];
    const int*   bond_adj    = (const int*)d_in[1];
    const float* dist_adj    = (const float*)d_in[2];
    const float* atom_tables = (const float*)d_in[3];
    const float* ga_means    = (const float*)d_in[4];
    const float* ga_stds     = (const float*)d_in[5];
    const float* ga_mul      = (const float*)d_in[6];
    const float* ga_bias     = (const float*)d_in[7];
    const float* graph_token = (const float*)d_in[8];
    const float* edge_tables = (const float*)d_in[9];
    const float* gb_means    = (const float*)d_in[10];
    const float* gb_stds     = (const float*)d_in[11];
    const float* gb_mul      = (const float*)d_in[12];
    const float* gb_bias     = (const float*)d_in[13];
    const float* egt         = (const float*)d_in[14];
    const float* in_proj_w   = (const float*)d_in[15];
    const float* in_proj_b   = (const float*)d_in[16];
    const float* out_proj_w  = (const float*)d_in[17];
    const float* out_proj_b  = (const float*)d_in[18];

    const size_t MROWS = (size_t)BB * NTOK;                   // 16640
    char* base = (char*)d_ws;
    unsigned short* x2  = (unsigned short*)base;              // 34.1 MB [16640][1024] (o2 reuses front half)
    float* qkv   = (float*)(base + MROWS * KK2 * 2);          // 102.2 MB [16640][1536]
    float* biasb = (float*)(base + MROWS * KK2 * 2 + MROWS * 3 * DD * 4);      // 69.2 MB
    unsigned short* wq2 = (unsigned short*)((char*)biasb + (size_t)BB * HH * NTOK * NTOK * 4); // 3.1 MB
    unsigned short* wo2 = wq2 + (size_t)3 * DD * KK2;         // 0.5 MB [512][512]

    k_cvt_wdup<<<dim3((3 * DD * DD + 255) / 256), 256, 0, stream>>>(in_proj_w, wq2, 3 * DD * DD);
    k_cvt_w<<<dim3((DD * DD + 255) / 256), 256, 0, stream>>>(out_proj_w, wo2, DD * DD);
    k_atom_embed<<<dim3(NTOK, BB), 256, 0, stream>>>(atom_fea, atom_tables, ga_means,
                                                     ga_stds, ga_mul, ga_bias, graph_token, x2);
    k_edge_bias<<<dim3(BB), 1024, 0, stream>>>(bond_adj, dist_adj, edge_tables, gb_means,
                                               gb_stds, gb_mul, gb_bias, egt, biasb);
    k_gemm_mfma<<<dim3(130, 12), 256, 0, stream>>>(x2, wq2, in_proj_b, qkv,
                                                   (int)MROWS, 3 * DD, KK2);
    k_attn<<<dim3(HH, BB), 256, 0, stream>>>(qkv, biasb, x2 /* o2: [16640][512] bf16 */);
    k_gemm_mfma<<<dim3(130, 4), 256, 0, stream>>>(x2, wo2, out_proj_b, (float*)d_out,
                                                  (int)MROWS, DD, DD);
}

// Round 12
// 462.535 us; speedup vs baseline: 1.2689x; 1.0639x over previous
//
#include <hip/hip_runtime.h>
#include <math.h>

#define BB 256
#define NAA 64
#define NTOK 65
#define DD 512
#define KK2 1024          // split-A doubled K (qkv projection)
#define HH 16
#define HDD 32
#define NGEFF 4           // bond values 0..15 -> bits 4,5 of (bond-1) always 0; table row 0 is 0
#define MAXP 50

typedef short bf16x8 __attribute__((ext_vector_type(8)));
typedef float f32x4 __attribute__((ext_vector_type(4)));

// single f32 -> bf16 RNE via gfx950 v_cvt_pk_bf16_f32 (1 VALU op vs ~6 bit-ops)
static __device__ __forceinline__ unsigned short f2b_rne(float f) {
    unsigned r;
    asm("v_cvt_pk_bf16_f32 %0, %1, 0" : "=v"(r) : "v"(f));
    return (unsigned short)r;
}
static __device__ __forceinline__ float b2f(unsigned short u) {
    return __uint_as_float(((unsigned)u) << 16);
}
static __device__ __forceinline__ void gload16(const void* g, void* l) {
    __builtin_amdgcn_global_load_lds(
        (const __attribute__((address_space(1))) unsigned int*)g,
        (__attribute__((address_space(3))) unsigned int*)l, 16, 0, 0);
}

// ---------------------------------------------------------------- weight converts
__global__ __launch_bounds__(256)
void k_cvt_wdup(const float* __restrict__ w, unsigned short* __restrict__ w2, int n)
{
    int i = blockIdx.x * 256 + threadIdx.x;
    if (i >= n) return;
    int row = i >> 9, k = i & 511;
    unsigned short v = f2b_rne(w[i]);
    w2[(size_t)row * KK2 + k] = v;
    w2[(size_t)row * KK2 + k + 512] = v;
}
__global__ __launch_bounds__(256)
void k_cvt_w(const float* __restrict__ w, unsigned short* __restrict__ w2, int n)
{
    int i = blockIdx.x * 256 + threadIdx.x;
    if (i >= n) return;
    w2[i] = f2b_rne(w[i]);
}

// ---------------------------------------------------------------- atom embed -> split bf16
__global__ __launch_bounds__(256)
void k_atom_embed(const int* __restrict__ atom_fea,          // [B][7][64]
                  const float* __restrict__ atom_tables,     // [6][100][512]
                  const float* __restrict__ ga_means,        // [512]
                  const float* __restrict__ ga_stds,
                  const float* __restrict__ ga_mul,
                  const float* __restrict__ ga_bias,
                  const float* __restrict__ graph_token,     // [512]
                  unsigned short* __restrict__ x2)           // [B*65][1024] hi|lo
{
    int n = blockIdx.x;   // 0..64
    int b = blockIdx.y;
    int tid = threadIdx.x;
    unsigned short* xp = x2 + ((size_t)b * NTOK + n) * KK2;
    if (n == 0) {
        for (int d = tid; d < DD; d += 256) {
            float val = graph_token[d];
            unsigned short h = f2b_rne(val);
            xp[d] = h;
            xp[d + 512] = f2b_rne(val - b2f(h));
        }
        return;
    }
    int a = n - 1;
    int fea[6];
#pragma unroll
    for (int i = 0; i < 6; ++i) fea[i] = atom_fea[((b * 7) + i) * NAA + a];
    int ci = atom_fea[((b * 7) + 6) * NAA + a];
    float cont = (float)ci;
    float g = ga_mul[0] * cont + ga_bias[0];
    const float Ac = 2.5066268f;    // sqrt(2*3.14159)
    for (int d = tid; d < DD; d += 256) {
        float val = 0.f;
        if (ci != 0) {
            float sd = fabsf(ga_stds[d]) + 1e-5f;
            float t = (g - ga_means[d]) / sd;
            val = expf(-0.5f * t * t) / (Ac * sd);
        }
#pragma unroll
        for (int i = 0; i < 6; ++i)
            val += atom_tables[((i * 100) + fea[i]) * DD + d];
        unsigned short h = f2b_rne(val);
        xp[d] = h;
        xp[d + 512] = f2b_rne(val - b2f(h));
    }
}

// ---------------------------------------------------------------- edge bias (fully LDS-resident)
__global__ __launch_bounds__(1024)
void k_edge_bias(const int* __restrict__ bond_adj,           // [B][64][64]
                 const float* __restrict__ dist_adj,         // [B][64][64]
                 const float* __restrict__ edge_tables,      // [6][51][16]
                 const float* __restrict__ gb_means,         // [16]
                 const float* __restrict__ gb_stds,
                 const float* __restrict__ gb_mul,
                 const float* __restrict__ gb_bias,
                 const float* __restrict__ egt,              // [16]
                 float* __restrict__ biasb)                  // [B][16][65][65]
{
    int b = blockIdx.x;
    int tid = threadIdx.x;
    __shared__ float s_j[64 * 65];
    __shared__ float s_jn[64 * 65];
    __shared__ unsigned long long s_brow[64];
    __shared__ unsigned char s_idx[16][4096];      // [t*4+hop][p]
    __shared__ float s_et[4][51][17];
    __shared__ int s_bond[4096];
    __shared__ float s_gmn[16], s_gis[16], s_gcf[16], s_egt[16];

    const int* badj = bond_adj + (size_t)b * 4096;
    const float Ac = 2.5066268f;

    for (int q = tid; q < 4096; q += 1024) s_bond[q] = badj[q];
    for (int q = tid; q < 4 * 51 * 16; q += 1024) {
        int t = q >> 4;
        int hh = q & 15;
        s_et[t / 51][t % 51][hh] = edge_tables[q];
    }
    if (tid < 16) {
        float sd = fabsf(gb_stds[tid]) + 1e-5f;
        s_gmn[tid] = gb_means[tid];
        s_gis[tid] = 1.f / sd;
        s_gcf[tid] = 1.f / (Ac * sd);
        s_egt[tid] = egt[tid];
    }
    __syncthreads();

    for (int t = 0; t < NGEFF; ++t) {
        for (int q = tid; q < 4096; q += 1024) {
            int bd = s_bond[q];
            int bit = (bd > 0) ? ((bd - 1) >> t) & 1 : 0;
            unsigned long long m = __ballot(bit != 0);
            if ((q & 63) == 0) s_brow[q >> 6] = m;
            s_j[(q >> 6) * 65 + (q & 63)] = (float)bit;
            s_idx[t * 4][q] = (unsigned char)bit;
        }
        __syncthreads();
        float* cur = s_j;
        float* nxt = s_jn;
        for (int hop = 1; hop < 4; ++hop) {
            int r = tid >> 4;
            int c0 = (tid & 15) << 2;
            float a0 = 0.f, a1 = 0.f, a2 = 0.f, a3 = 0.f;
            for (int k = 0; k < 64; ++k) {
                float jv = cur[r * 65 + k];
                unsigned int rs = (unsigned int)(s_brow[k] >> c0);
                a0 += (rs & 1u) ? jv : 0.f;
                a1 += (rs & 2u) ? jv : 0.f;
                a2 += (rs & 4u) ? jv : 0.f;
                a3 += (rs & 8u) ? jv : 0.f;
            }
            nxt[r * 65 + c0 + 0] = a0;
            nxt[r * 65 + c0 + 1] = a1;
            nxt[r * 65 + c0 + 2] = a2;
            nxt[r * 65 + c0 + 3] = a3;
            int p0 = r * 64 + c0;
            int i0 = (int)a0; if (i0 > MAXP) i0 = MAXP;
            int i1 = (int)a1; if (i1 > MAXP) i1 = MAXP;
            int i2 = (int)a2; if (i2 > MAXP) i2 = MAXP;
            int i3 = (int)a3; if (i3 > MAXP) i3 = MAXP;
            s_idx[t * 4 + hop][p0 + 0] = (unsigned char)i0;
            s_idx[t * 4 + hop][p0 + 1] = (unsigned char)i1;
            s_idx[t * 4 + hop][p0 + 2] = (unsigned char)i2;
            s_idx[t * 4 + hop][p0 + 3] = (unsigned char)i3;
            __syncthreads();
            float* tmp = cur; cur = nxt; nxt = tmp;
        }
    }

    float* bb = biasb + (size_t)b * HH * NTOK * NTOK;
    for (int i = tid; i < HH * NTOK; i += 1024) {
        int hh = i / NTOK, j = i - hh * NTOK;
        float e = s_egt[hh];
        bb[(hh * NTOK + 0) * NTOK + j] = e;
        bb[(hh * NTOK + j) * NTOK + 0] = e;
    }
    float gm = gb_mul[0], gbi = gb_bias[0];
    for (int p = tid; p < 4096; p += 1024) {
        int a1i = p >> 6, a2i = p & 63;
        float dist = dist_adj[(size_t)b * 4096 + p];
        float g = gm * dist + gbi;
        float mv = (s_bond[p] != 0) ? 0.f : -INFINITY;
        int ixs[16];
#pragma unroll
        for (int q = 0; q < 16; ++q) ixs[q] = s_idx[q][p];
#pragma unroll
        for (int hh = 0; hh < 16; ++hh) {
            float v = 0.f;
            if (dist != 0.f) {
                float tt = (g - s_gmn[hh]) * s_gis[hh];
                v = expf(-0.5f * tt * tt) * s_gcf[hh];
            }
#pragma unroll
            for (int q = 0; q < 16; ++q) v += s_et[q >> 2][ixs[q]][hh];
            bb[(hh * NTOK + a1i + 1) * NTOK + (a2i + 1)] = v + mv;
        }
    }
}

// ---------------------------------------------------------------- MFMA GEMM
#define TM 128
#define TN 128
#define TBK 32
__global__ __launch_bounds__(256)
void k_gemm_mfma(const unsigned short* __restrict__ A,
                 const unsigned short* __restrict__ W,
                 const float* __restrict__ bias,
                 float* __restrict__ C,
                 int M, int N, int KK)
{
    __shared__ short sA[TM * TBK];   // 8 KB
    __shared__ short sB[TN * TBK];   // 8 KB
    int tid = threadIdx.x;
    int lane = tid & 63, w = tid >> 6;
    int wm = w >> 1, wn = w & 1;
    int row0 = blockIdx.x * TM, col0 = blockIdx.y * TN;

    f32x4 zf = {0.f, 0.f, 0.f, 0.f};
    f32x4 acc[4][4];
#pragma unroll
    for (int m = 0; m < 4; ++m)
#pragma unroll
        for (int n = 0; n < 4; ++n) acc[m][n] = zf;

    int srow = tid >> 2;
    int skoff = (tid & 3) << 3;
    const unsigned short* gA0 = A + (size_t)(row0 + srow) * KK + skoff;
    const unsigned short* gA1 = A + (size_t)(row0 + srow + 64) * KK + skoff;
    const unsigned short* gB0 = W + (size_t)(col0 + srow) * KK + skoff;
    const unsigned short* gB1 = W + (size_t)(col0 + srow + 64) * KK + skoff;
    short* lA0 = sA + tid * 8;
    short* lA1 = sA + 2048 + tid * 8;
    short* lB0 = sB + tid * 8;
    short* lB1 = sB + 2048 + tid * 8;

    int fk = (lane >> 4) << 3;    // k-chunk 0,8,16,24
    int fr = lane & 15;           // row/col within fragment

    for (int kb = 0; kb < KK; kb += TBK) {
        gload16(gA0 + kb, lA0);
        gload16(gA1 + kb, lA1);
        gload16(gB0 + kb, lB0);
        gload16(gB1 + kb, lB1);
        __syncthreads();
        bf16x8 af[4], bg[4];
#pragma unroll
        for (int m = 0; m < 4; ++m)
            af[m] = *(const bf16x8*)&sA[(wm * 64 + m * 16 + fr) * TBK + fk];
#pragma unroll
        for (int n = 0; n < 4; ++n)
            bg[n] = *(const bf16x8*)&sB[(wn * 64 + n * 16 + fr) * TBK + fk];
#pragma unroll
        for (int m = 0; m < 4; ++m)
#pragma unroll
            for (int n = 0; n < 4; ++n)
                acc[m][n] = __builtin_amdgcn_mfma_f32_16x16x32_bf16(af[m], bg[n], acc[m][n], 0, 0, 0);
        __syncthreads();
    }

    int crg = (lane >> 4) << 2;   // row=(lane>>4)*4+reg, col=lane&15
#pragma unroll
    for (int m = 0; m < 4; ++m) {
#pragma unroll
        for (int n = 0; n < 4; ++n) {
            int col = col0 + wn * 64 + n * 16 + fr;
            float bv = bias[col];
            int rowb = row0 + wm * 64 + m * 16 + crg;
#pragma unroll
            for (int r = 0; r < 4; ++r)
                C[(size_t)(rowb + r) * N + col] = acc[m][n][r] + bv;
        }
    }
}

// ---------------------------------------------------------------- attention via MFMA, fragment-order LDS
// LDS plan (49.3 KB -> 3 blocks/CU):
//   [0,20480)      Qh|Ql|Kh|Kl (2560 u16 each)  -- dead after score MFMAs
//   [20480,38160)  SP f32 [65][68]              -- scores / softmax
//   [0,30720)      P frag (30 x 512 u16), ALIASES Q/K + SP[rows 0..37]
//                  safe: convert register-stages ALL SP reads before the barrier
//   [38160,50448)  Vh|Vl (3072 u16 each)
__global__ __launch_bounds__(256)
void k_attn(const float* __restrict__ qkv,   // [B][65][1536]
            const float* __restrict__ biasb, // [B][16][65][65]
            unsigned short* __restrict__ o2) // [B*65][512] bf16
{
    int h = blockIdx.x, b = blockIdx.y;
    int tid = threadIdx.x;
    int lane = tid & 63, w = tid >> 6;
    __shared__ __align__(16) char smem[50448];
    unsigned short* Qh = (unsigned short*)smem;
    unsigned short* Ql = Qh + 2560;
    unsigned short* Kh = Qh + 5120;
    unsigned short* Kl = Qh + 7680;
    float*          SP = (float*)(smem + 20480);          // [65][68]
    unsigned short* SPu = (unsigned short*)smem;          // P frag alias
    unsigned short* Vh = (unsigned short*)(smem + 38160);
    unsigned short* Vl = Vh + 3072;

    const float scale = 0.17677669529663687f;   // 1/sqrt(32)
    const float* qb = qkv + (size_t)b * NTOK * (3 * DD) + h * HDD;

    // fill (fragment-order) + zero-pad tails
    for (int i = tid; i < NTOK * HDD; i += 256) {
        int n = i >> 5, d = i & 31;
        const float* row = qb + (size_t)n * (3 * DD);
        float q = row[d] * scale, k = row[DD + d], v = row[2 * DD + d];
        int qa = (((n >> 4) * 4 + (d >> 3)) * 16 + (n & 15)) * 8 + (d & 7);
        unsigned short qh = f2b_rne(q);
        Qh[qa] = qh; Ql[qa] = f2b_rne(q - b2f(qh));
        unsigned short kh = f2b_rne(k);
        Kh[qa] = kh; Kl[qa] = f2b_rne(k - b2f(kh));
        int va = ((((d >> 4) * 3 + (n >> 5)) * 4 + ((n & 31) >> 3)) * 16 + (d & 15)) * 8 + (n & 7);
        unsigned short vh = f2b_rne(v);
        Vh[va] = vh; Vl[va] = f2b_rne(v - b2f(vh));
    }
    for (int i = tid; i < 480; i += 256) {          // Q/K rows n=65..79
        int n = 65 + (i >> 5), d = i & 31;
        int qa = (((n >> 4) * 4 + (d >> 3)) * 16 + (n & 15)) * 8 + (d & 7);
        Qh[qa] = 0; Ql[qa] = 0; Kh[qa] = 0; Kl[qa] = 0;
    }
    for (int i = tid; i < 992; i += 256) {          // V cols n=65..95
        int n = 65 + (i >> 5), d = i & 31;
        int va = ((((d >> 4) * 3 + (n >> 5)) * 4 + ((n & 31) >> 3)) * 16 + (d & 15)) * 8 + (n & 7);
        Vh[va] = 0; Vl[va] = 0;
    }
    __syncthreads();

    int fr = lane & 15, fc = lane >> 4;
    // scores: 25 tiles, conflict-free lane-linear fragment reads
    const float* bp = biasb + (((size_t)b * HH + h) * NTOK) * NTOK;
    for (int t = w; t < 25; t += 4) {
        int rt = t / 5, ct = t % 5;
        bf16x8 aQh = *(const bf16x8*)&Qh[rt * 512 + lane * 8];
        bf16x8 aQl = *(const bf16x8*)&Ql[rt * 512 + lane * 8];
        bf16x8 bKh = *(const bf16x8*)&Kh[ct * 512 + lane * 8];
        bf16x8 bKl = *(const bf16x8*)&Kl[ct * 512 + lane * 8];
        f32x4 acc = {0.f, 0.f, 0.f, 0.f};
        acc = __builtin_amdgcn_mfma_f32_16x16x32_bf16(aQh, bKh, acc, 0, 0, 0);
        acc = __builtin_amdgcn_mfma_f32_16x16x32_bf16(aQh, bKl, acc, 0, 0, 0);
        acc = __builtin_amdgcn_mfma_f32_16x16x32_bf16(aQl, bKh, acc, 0, 0, 0);
        int col = ct * 16 + fr;
#pragma unroll
        for (int r = 0; r < 4; ++r) {
            int row = rt * 16 + fc * 4 + r;
            if (row < 65 && col < 65)
                SP[row * 68 + col] = acc[r] + bp[row * NTOK + col];
        }
    }
    __syncthreads();

    // softmax: 16-lane groups, 4 rows per wave per sweep
    for (int sweep = 0; sweep < 5; ++sweep) {
        int i = sweep * 16 + w * 4 + fc;
        if (i < 65) {
            float pv[5];
            float mx = -INFINITY;
#pragma unroll
            for (int q = 0; q < 5; ++q) {
                int c = fr + q * 16;
                pv[q] = (c < 65) ? SP[i * 68 + c] : -INFINITY;
                mx = fmaxf(mx, pv[q]);
            }
#pragma unroll
            for (int off = 1; off < 16; off <<= 1) mx = fmaxf(mx, __shfl_xor(mx, off));
            float sum = 0.f;
#pragma unroll
            for (int q = 0; q < 5; ++q) { pv[q] = expf(pv[q] - mx); sum += pv[q]; }
#pragma unroll
            for (int off = 1; off < 16; off <<= 1) sum += __shfl_xor(sum, off);
            float inv = 1.f / sum;
#pragma unroll
            for (int q = 0; q < 5; ++q) {
                int c = fr + q * 16;
                if (c < 65) SP[i * 68 + c] = pv[q] * inv;
            }
        }
    }
    __syncthreads();

    // P -> hi/lo bf16 fragment-order (register-staged: ALL reads before barrier,
    // then writes clobber the Q/K+SP alias region)
    int cl = tid >> 3, cj = tid & 7;       // chunk-lane base, j within chunk
    float pr[30];
    {
        int cnt = 0;
#pragma unroll
        for (int rt = 0; rt < 5; ++rt)
#pragma unroll
            for (int kc = 0; kc < 3; ++kc)
#pragma unroll
                for (int s = 0; s < 2; ++s) {
                    int lane2 = cl + s * 32;
                    int row = rt * 16 + (lane2 & 15);
                    int col = kc * 32 + (lane2 >> 4) * 8 + cj;
                    pr[cnt++] = (row < 65 && col < 65) ? SP[row * 68 + col] : 0.f;
                }
    }
    __syncthreads();
    {
        int cnt = 0;
#pragma unroll
        for (int rt = 0; rt < 5; ++rt)
#pragma unroll
            for (int kc = 0; kc < 3; ++kc)
#pragma unroll
                for (int s = 0; s < 2; ++s) {
                    int lane2 = cl + s * 32;
                    float p = pr[cnt++];
                    unsigned short hi = f2b_rne(p);
                    SPu[(rt * 6 + kc) * 512 + lane2 * 8 + cj] = hi;
                    SPu[(rt * 6 + 3 + kc) * 512 + lane2 * 8 + cj] = f2b_rne(p - b2f(hi));
                }
    }
    __syncthreads();

    // PV: 10 tiles (5 rt x 2 ct), K=96 in 3 chunks, conflict-free reads
    unsigned short* ob = o2 + ((size_t)b * NTOK) * DD + h * HDD;
    for (int t = w; t < 10; t += 4) {
        int rt = t >> 1, ct = t & 1;
        f32x4 acc = {0.f, 0.f, 0.f, 0.f};
#pragma unroll
        for (int kc = 0; kc < 3; ++kc) {
            bf16x8 aPh = *(const bf16x8*)&SPu[(rt * 6 + kc) * 512 + lane * 8];
            bf16x8 aPl = *(const bf16x8*)&SPu[(rt * 6 + 3 + kc) * 512 + lane * 8];
            bf16x8 bVh = *(const bf16x8*)&Vh[(ct * 3 + kc) * 512 + lane * 8];
            bf16x8 bVl = *(const bf16x8*)&Vl[(ct * 3 + kc) * 512 + lane * 8];
            acc = __builtin_amdgcn_mfma_f32_16x16x32_bf16(aPh, bVh, acc, 0, 0, 0);
            acc = __builtin_amdgcn_mfma_f32_16x16x32_bf16(aPh, bVl, acc, 0, 0, 0);
            acc = __builtin_amdgcn_mfma_f32_16x16x32_bf16(aPl, bVh, acc, 0, 0, 0);
        }
        int d = ct * 16 + fr;
#pragma unroll
        for (int r = 0; r < 4; ++r) {
            int row = rt * 16 + fc * 4 + r;
            if (row < 65)
                ob[(size_t)row * DD + d] = f2b_rne(acc[r]);
        }
    }
}

// ---------------------------------------------------------------- launch
extern "C" void kernel_launch(void* const* d_in, const int* in_sizes, int n_in,
                              void* d_out, int out_size, void* d_ws, size_t ws_size,
                              hipStream_t stream)
{
    (void)in_sizes; (void)n_in; (void)out_size; (void)ws_size;
    const int*   atom_fea    = (const int*)d_in[0];
    const int*   bond_adj    = (const int*)d_in[1];
    const float* dist_adj    = (const float*)d_in[2];
    const float* atom_tables = (const float*)d_in[3];
    const float* ga_means    = (const float*)d_in[4];
    const float* ga_stds     = (const float*)d_in[5];
    const float* ga_mul      = (const float*)d_in[6];
    const float* ga_bias     = (const float*)d_in[7];
    const float* graph_token = (const float*)d_in[8];
    const float* edge_tables = (const float*)d_in[9];
    const float* gb_means    = (const float*)d_in[10];
    const float* gb_stds     = (const float*)d_in[11];
    const float* gb_mul      = (const float*)d_in[12];
    const float* gb_bias     = (const float*)d_in[13];
    const float* egt         = (const float*)d_in[14];
    const float* in_proj_w   = (const float*)d_in[15];
    const float* in_proj_b   = (const float*)d_in[16];
    const float* out_proj_w  = (const float*)d_in[17];
    const float* out_proj_b  = (const float*)d_in[18];

    const size_t MROWS = (size_t)BB * NTOK;                   // 16640
    char* base = (char*)d_ws;
    unsigned short* x2  = (unsigned short*)base;              // 34.1 MB [16640][1024] (o2 reuses front half)
    float* qkv   = (float*)(base + MROWS * KK2 * 2);          // 102.2 MB [16640][1536]
    float* biasb = (float*)(base + MROWS * KK2 * 2 + MROWS * 3 * DD * 4);      // 69.2 MB
    unsigned short* wq2 = (unsigned short*)((char*)biasb + (size_t)BB * HH * NTOK * NTOK * 4); // 3.1 MB
    unsigned short* wo2 = wq2 + (size_t)3 * DD * KK2;         // 0.5 MB [512][512]

    k_cvt_wdup<<<dim3((3 * DD * DD + 255) / 256), 256, 0, stream>>>(in_proj_w, wq2, 3 * DD * DD);
    k_cvt_w<<<dim3((DD * DD + 255) / 256), 256, 0, stream>>>(out_proj_w, wo2, DD * DD);
    k_atom_embed<<<dim3(NTOK, BB), 256, 0, stream>>>(atom_fea, atom_tables, ga_means,
                                                     ga_stds, ga_mul, ga_bias, graph_token, x2);
    k_edge_bias<<<dim3(BB), 1024, 0, stream>>>(bond_adj, dist_adj, edge_tables, gb_means,
                                               gb_stds, gb_mul, gb_bias, egt, biasb);
    k_gemm_mfma<<<dim3(130, 12), 256, 0, stream>>>(x2, wq2, in_proj_b, qkv,
                                                   (int)MROWS, 3 * DD, KK2);
    k_attn<<<dim3(HH, BB), 256, 0, stream>>>(qkv, biasb, x2 /* o2: [16640][512] bf16 */);
    k_gemm_mfma<<<dim3(130, 4), 256, 0, stream>>>(x2, wo2, out_proj_b, (float*)d_out,
                                                  (int)MROWS, DD, DD);
}

// Round 13
// 400.515 us; speedup vs baseline: 1.4654x; 1.1548x over previous
//
#include <hip/hip_runtime.h>
#include <math.h>

#define BB 256
#define NAA 64
#define NTOK 65
#define DD 512
#define KK2 1024          // split-A doubled K (qkv projection)
#define HH 16
#define HDD 32
#define NGEFF 4           // bond values 0..15 -> bits 4,5 of (bond-1) always 0; table row 0 is 0
#define MAXP 50

typedef short bf16x8 __attribute__((ext_vector_type(8)));
typedef float f32x4 __attribute__((ext_vector_type(4)));

// single f32 -> bf16 RNE via gfx950 v_cvt_pk_bf16_f32 (1 VALU op vs ~6 bit-ops)
static __device__ __forceinline__ unsigned short f2b_rne(float f) {
    unsigned r;
    asm("v_cvt_pk_bf16_f32 %0, %1, 0" : "=v"(r) : "v"(f));
    return (unsigned short)r;
}
static __device__ __forceinline__ float b2f(unsigned short u) {
    return __uint_as_float(((unsigned)u) << 16);
}
static __device__ __forceinline__ void gload16(const void* g, void* l) {
    __builtin_amdgcn_global_load_lds(
        (const __attribute__((address_space(1))) unsigned int*)g,
        (__attribute__((address_space(3))) unsigned int*)l, 16, 0, 0);
}

// ---------------------------------------------------------------- weight converts
__global__ __launch_bounds__(256)
void k_cvt_wdup(const float* __restrict__ w, unsigned short* __restrict__ w2, int n)
{
    int i = blockIdx.x * 256 + threadIdx.x;
    if (i >= n) return;
    int row = i >> 9, k = i & 511;
    unsigned short v = f2b_rne(w[i]);
    w2[(size_t)row * KK2 + k] = v;
    w2[(size_t)row * KK2 + k + 512] = v;
}
__global__ __launch_bounds__(256)
void k_cvt_w(const float* __restrict__ w, unsigned short* __restrict__ w2, int n)
{
    int i = blockIdx.x * 256 + threadIdx.x;
    if (i >= n) return;
    w2[i] = f2b_rne(w[i]);
}

// ---------------------------------------------------------------- atom embed -> split bf16
__global__ __launch_bounds__(256)
void k_atom_embed(const int* __restrict__ atom_fea,          // [B][7][64]
                  const float* __restrict__ atom_tables,     // [6][100][512]
                  const float* __restrict__ ga_means,        // [512]
                  const float* __restrict__ ga_stds,
                  const float* __restrict__ ga_mul,
                  const float* __restrict__ ga_bias,
                  const float* __restrict__ graph_token,     // [512]
                  unsigned short* __restrict__ x2)           // [B*65][1024] hi|lo
{
    int n = blockIdx.x;   // 0..64
    int b = blockIdx.y;
    int tid = threadIdx.x;
    unsigned short* xp = x2 + ((size_t)b * NTOK + n) * KK2;
    if (n == 0) {
        for (int d = tid; d < DD; d += 256) {
            float val = graph_token[d];
            unsigned short h = f2b_rne(val);
            xp[d] = h;
            xp[d + 512] = f2b_rne(val - b2f(h));
        }
        return;
    }
    int a = n - 1;
    int fea[6];
#pragma unroll
    for (int i = 0; i < 6; ++i) fea[i] = atom_fea[((b * 7) + i) * NAA + a];
    int ci = atom_fea[((b * 7) + 6) * NAA + a];
    float cont = (float)ci;
    float g = ga_mul[0] * cont + ga_bias[0];
    const float Ac = 2.5066268f;    // sqrt(2*3.14159)
    for (int d = tid; d < DD; d += 256) {
        float val = 0.f;
        if (ci != 0) {
            float sd = fabsf(ga_stds[d]) + 1e-5f;
            float t = (g - ga_means[d]) / sd;
            val = expf(-0.5f * t * t) / (Ac * sd);
        }
#pragma unroll
        for (int i = 0; i < 6; ++i)
            val += atom_tables[((i * 100) + fea[i]) * DD + d];
        unsigned short h = f2b_rne(val);
        xp[d] = h;
        xp[d + 512] = f2b_rne(val - b2f(h));
    }
}

// ---------------------------------------------------------------- edge bias (LDS-resident, sparse)
__global__ __launch_bounds__(1024)
void k_edge_bias(const int* __restrict__ bond_adj,           // [B][64][64]
                 const float* __restrict__ dist_adj,         // [B][64][64]
                 const float* __restrict__ edge_tables,      // [6][51][16]
                 const float* __restrict__ gb_means,         // [16]
                 const float* __restrict__ gb_stds,
                 const float* __restrict__ gb_mul,
                 const float* __restrict__ gb_bias,
                 const float* __restrict__ egt,              // [16]
                 float* __restrict__ biasb)                  // [B][16][65][65]
{
    int b = blockIdx.x;
    int tid = threadIdx.x;
    __shared__ float s_j[64 * 65];
    __shared__ float s_jn[64 * 65];
    __shared__ unsigned long long s_brow[64];
    __shared__ unsigned long long s_bcol[64];
    __shared__ unsigned char s_idx[16][4096];      // [t*4+hop][p]
    __shared__ float s_et[4][51][20];              // stride 20 -> 16B-aligned rows
    __shared__ int s_bond[4096];
    __shared__ float s_gmn[16], s_gis[16], s_gcf[16], s_egt[16];

    const int* badj = bond_adj + (size_t)b * 4096;
    const float Ac = 2.5066268f;

    for (int q = tid; q < 4096; q += 1024) s_bond[q] = badj[q];
    for (int q = tid; q < 4 * 51 * 16; q += 1024) {
        int t = q >> 4;                 // combined (tt*51+idx)
        int hh = q & 15;
        s_et[t / 51][t % 51][hh] = edge_tables[q];
    }
    if (tid < 16) {
        float sd = fabsf(gb_stds[tid]) + 1e-5f;
        s_gmn[tid] = gb_means[tid];
        s_gis[tid] = 1.f / sd;
        s_gcf[tid] = 1.f / (Ac * sd);
        s_egt[tid] = egt[tid];
    }
    __syncthreads();

    for (int t = 0; t < NGEFF; ++t) {
        for (int q = tid; q < 4096; q += 1024) {
            int bd = s_bond[q];
            int bit = (bd > 0) ? ((bd - 1) >> t) & 1 : 0;
            unsigned long long m = __ballot(bit != 0);
            if ((q & 63) == 0) s_brow[q >> 6] = m;
            s_j[(q >> 6) * 65 + (q & 63)] = (float)bit;
            s_idx[t * 4][q] = (unsigned char)bit;
        }
        __syncthreads();
        if (tid < 64) {                 // column masks (transpose of s_brow)
            unsigned long long m = 0;
            for (int r = 0; r < 64; ++r)
                m |= ((s_brow[r] >> tid) & 1ULL) << r;
            s_bcol[tid] = m;
        }
        __syncthreads();
        float* cur = s_j;
        float* nxt = s_jn;
        for (int hop = 1; hop < 4; ++hop) {
            int r = tid >> 4;
            int c0 = (tid & 15) << 2;
            const float* curr = &cur[r * 65];
#pragma unroll
            for (int j = 0; j < 4; ++j) {
                int c = c0 + j;
                unsigned long long mask = s_bcol[c];
                float acc = 0.f;
                while (mask) {                       // ~4 set bits avg vs 64 dense iters
                    int k = __builtin_ctzll(mask);
                    acc += curr[k];
                    mask &= mask - 1;
                }
                nxt[r * 65 + c] = acc;
                int iv = (int)acc; if (iv > MAXP) iv = MAXP;
                s_idx[t * 4 + hop][r * 64 + c] = (unsigned char)iv;
            }
            __syncthreads();
            float* tmp = cur; cur = nxt; nxt = tmp;
        }
    }

    float* bb = biasb + (size_t)b * HH * NTOK * NTOK;
    for (int i = tid; i < HH * NTOK; i += 1024) {
        int hh = i / NTOK, j = i - hh * NTOK;
        float e = s_egt[hh];
        bb[(hh * NTOK + 0) * NTOK + j] = e;
        bb[(hh * NTOK + j) * NTOK + 0] = e;
    }
    float gm = gb_mul[0], gbi = gb_bias[0];
    for (int p = tid; p < 4096; p += 1024) {
        int a1i = p >> 6, a2i = p & 63;
        float dist = dist_adj[(size_t)b * 4096 + p];
        float g = gm * dist + gbi;
        float mv = (s_bond[p] != 0) ? 0.f : -INFINITY;
        float v[16];
        if (dist != 0.f) {
#pragma unroll
            for (int hh = 0; hh < 16; ++hh) {
                float tt = (g - s_gmn[hh]) * s_gis[hh];
                v[hh] = expf(-0.5f * tt * tt) * s_gcf[hh];
            }
        } else {
#pragma unroll
            for (int hh = 0; hh < 16; ++hh) v[hh] = 0.f;
        }
#pragma unroll
        for (int q = 0; q < 16; ++q) {
            int ix = s_idx[q][p];
            if (ix) {                                // row 0 is all-zero: skip is exact
                const float* et = &s_et[q >> 2][ix][0];
                float4 e0 = *(const float4*)(et + 0);
                float4 e1 = *(const float4*)(et + 4);
                float4 e2 = *(const float4*)(et + 8);
                float4 e3 = *(const float4*)(et + 12);
                v[0] += e0.x;  v[1] += e0.y;  v[2] += e0.z;  v[3] += e0.w;
                v[4] += e1.x;  v[5] += e1.y;  v[6] += e1.z;  v[7] += e1.w;
                v[8] += e2.x;  v[9] += e2.y;  v[10] += e2.z; v[11] += e2.w;
                v[12] += e3.x; v[13] += e3.y; v[14] += e3.z; v[15] += e3.w;
            }
        }
#pragma unroll
        for (int hh = 0; hh < 16; ++hh)
            bb[(hh * NTOK + a1i + 1) * NTOK + (a2i + 1)] = v[hh] + mv;
    }
}

// ---------------------------------------------------------------- MFMA GEMM
#define TM 128
#define TN 128
#define TBK 32
__global__ __launch_bounds__(256)
void k_gemm_mfma(const unsigned short* __restrict__ A,
                 const unsigned short* __restrict__ W,
                 const float* __restrict__ bias,
                 float* __restrict__ C,
                 int M, int N, int KK)
{
    __shared__ short sA[TM * TBK];   // 8 KB
    __shared__ short sB[TN * TBK];   // 8 KB
    int tid = threadIdx.x;
    int lane = tid & 63, w = tid >> 6;
    int wm = w >> 1, wn = w & 1;
    int row0 = blockIdx.x * TM, col0 = blockIdx.y * TN;

    f32x4 zf = {0.f, 0.f, 0.f, 0.f};
    f32x4 acc[4][4];
#pragma unroll
    for (int m = 0; m < 4; ++m)
#pragma unroll
        for (int n = 0; n < 4; ++n) acc[m][n] = zf;

    int srow = tid >> 2;
    int skoff = (tid & 3) << 3;
    const unsigned short* gA0 = A + (size_t)(row0 + srow) * KK + skoff;
    const unsigned short* gA1 = A + (size_t)(row0 + srow + 64) * KK + skoff;
    const unsigned short* gB0 = W + (size_t)(col0 + srow) * KK + skoff;
    const unsigned short* gB1 = W + (size_t)(col0 + srow + 64) * KK + skoff;
    short* lA0 = sA + tid * 8;
    short* lA1 = sA + 2048 + tid * 8;
    short* lB0 = sB + tid * 8;
    short* lB1 = sB + 2048 + tid * 8;

    int fk = (lane >> 4) << 3;    // k-chunk 0,8,16,24
    int fr = lane & 15;           // row/col within fragment

    for (int kb = 0; kb < KK; kb += TBK) {
        gload16(gA0 + kb, lA0);
        gload16(gA1 + kb, lA1);
        gload16(gB0 + kb, lB0);
        gload16(gB1 + kb, lB1);
        __syncthreads();
        bf16x8 af[4], bg[4];
#pragma unroll
        for (int m = 0; m < 4; ++m)
            af[m] = *(const bf16x8*)&sA[(wm * 64 + m * 16 + fr) * TBK + fk];
#pragma unroll
        for (int n = 0; n < 4; ++n)
            bg[n] = *(const bf16x8*)&sB[(wn * 64 + n * 16 + fr) * TBK + fk];
#pragma unroll
        for (int m = 0; m < 4; ++m)
#pragma unroll
            for (int n = 0; n < 4; ++n)
                acc[m][n] = __builtin_amdgcn_mfma_f32_16x16x32_bf16(af[m], bg[n], acc[m][n], 0, 0, 0);
        __syncthreads();
    }

    int crg = (lane >> 4) << 2;   // row=(lane>>4)*4+reg, col=lane&15
#pragma unroll
    for (int m = 0; m < 4; ++m) {
#pragma unroll
        for (int n = 0; n < 4; ++n) {
            int col = col0 + wn * 64 + n * 16 + fr;
            float bv = bias[col];
            int rowb = row0 + wm * 64 + m * 16 + crg;
#pragma unroll
            for (int r = 0; r < 4; ++r)
                C[(size_t)(rowb + r) * N + col] = acc[m][n][r] + bv;
        }
    }
}

// ---------------------------------------------------------------- attention via MFMA, fragment-order LDS
// LDS plan (49.3 KB -> 3 blocks/CU):
//   [0,20480)      Qh|Ql|Kh|Kl (2560 u16 each)  -- dead after score MFMAs
//   [20480,38160)  SP f32 [65][68]              -- scores / softmax
//   [0,30720)      P frag (30 x 512 u16), ALIASES Q/K + SP[rows 0..37]
//                  safe: convert register-stages ALL SP reads before the barrier
//   [38160,50448)  Vh|Vl (3072 u16 each)
__global__ __launch_bounds__(256)
void k_attn(const float* __restrict__ qkv,   // [B][65][1536]
            const float* __restrict__ biasb, // [B][16][65][65]
            unsigned short* __restrict__ o2) // [B*65][512] bf16
{
    int h = blockIdx.x, b = blockIdx.y;
    int tid = threadIdx.x;
    int lane = tid & 63, w = tid >> 6;
    __shared__ __align__(16) char smem[50448];
    unsigned short* Qh = (unsigned short*)smem;
    unsigned short* Ql = Qh + 2560;
    unsigned short* Kh = Qh + 5120;
    unsigned short* Kl = Qh + 7680;
    float*          SP = (float*)(smem + 20480);          // [65][68]
    unsigned short* SPu = (unsigned short*)smem;          // P frag alias
    unsigned short* Vh = (unsigned short*)(smem + 38160);
    unsigned short* Vl = Vh + 3072;

    const float scale = 0.17677669529663687f;   // 1/sqrt(32)
    const float* qb = qkv + (size_t)b * NTOK * (3 * DD) + h * HDD;

    // fill (fragment-order) + zero-pad tails
    for (int i = tid; i < NTOK * HDD; i += 256) {
        int n = i >> 5, d = i & 31;
        const float* row = qb + (size_t)n * (3 * DD);
        float q = row[d] * scale, k = row[DD + d], v = row[2 * DD + d];
        int qa = (((n >> 4) * 4 + (d >> 3)) * 16 + (n & 15)) * 8 + (d & 7);
        unsigned short qh = f2b_rne(q);
        Qh[qa] = qh; Ql[qa] = f2b_rne(q - b2f(qh));
        unsigned short kh = f2b_rne(k);
        Kh[qa] = kh; Kl[qa] = f2b_rne(k - b2f(kh));
        int va = ((((d >> 4) * 3 + (n >> 5)) * 4 + ((n & 31) >> 3)) * 16 + (d & 15)) * 8 + (n & 7);
        unsigned short vh = f2b_rne(v);
        Vh[va] = vh; Vl[va] = f2b_rne(v - b2f(vh));
    }
    for (int i = tid; i < 480; i += 256) {          // Q/K rows n=65..79
        int n = 65 + (i >> 5), d = i & 31;
        int qa = (((n >> 4) * 4 + (d >> 3)) * 16 + (n & 15)) * 8 + (d & 7);
        Qh[qa] = 0; Ql[qa] = 0; Kh[qa] = 0; Kl[qa] = 0;
    }
    for (int i = tid; i < 992; i += 256) {          // V cols n=65..95
        int n = 65 + (i >> 5), d = i & 31;
        int va = ((((d >> 4) * 3 + (n >> 5)) * 4 + ((n & 31) >> 3)) * 16 + (d & 15)) * 8 + (n & 7);
        Vh[va] = 0; Vl[va] = 0;
    }
    __syncthreads();

    int fr = lane & 15, fc = lane >> 4;
    // scores: 25 tiles, conflict-free lane-linear fragment reads
    const float* bp = biasb + (((size_t)b * HH + h) * NTOK) * NTOK;
    for (int t = w; t < 25; t += 4) {
        int rt = t / 5, ct = t % 5;
        bf16x8 aQh = *(const bf16x8*)&Qh[rt * 512 + lane * 8];
        bf16x8 aQl = *(const bf16x8*)&Ql[rt * 512 + lane * 8];
        bf16x8 bKh = *(const bf16x8*)&Kh[ct * 512 + lane * 8];
        bf16x8 bKl = *(const bf16x8*)&Kl[ct * 512 + lane * 8];
        f32x4 acc = {0.f, 0.f, 0.f, 0.f};
        acc = __builtin_amdgcn_mfma_f32_16x16x32_bf16(aQh, bKh, acc, 0, 0, 0);
        acc = __builtin_amdgcn_mfma_f32_16x16x32_bf16(aQh, bKl, acc, 0, 0, 0);
        acc = __builtin_amdgcn_mfma_f32_16x16x32_bf16(aQl, bKh, acc, 0, 0, 0);
        int col = ct * 16 + fr;
#pragma unroll
        for (int r = 0; r < 4; ++r) {
            int row = rt * 16 + fc * 4 + r;
            if (row < 65 && col < 65)
                SP[row * 68 + col] = acc[r] + bp[row * NTOK + col];
        }
    }
    __syncthreads();

    // softmax: 16-lane groups, 4 rows per wave per sweep
    for (int sweep = 0; sweep < 5; ++sweep) {
        int i = sweep * 16 + w * 4 + fc;
        if (i < 65) {
            float pv[5];
            float mx = -INFINITY;
#pragma unroll
            for (int q = 0; q < 5; ++q) {
                int c = fr + q * 16;
                pv[q] = (c < 65) ? SP[i * 68 + c] : -INFINITY;
                mx = fmaxf(mx, pv[q]);
            }
#pragma unroll
            for (int off = 1; off < 16; off <<= 1) mx = fmaxf(mx, __shfl_xor(mx, off));
            float sum = 0.f;
#pragma unroll
            for (int q = 0; q < 5; ++q) { pv[q] = expf(pv[q] - mx); sum += pv[q]; }
#pragma unroll
            for (int off = 1; off < 16; off <<= 1) sum += __shfl_xor(sum, off);
            float inv = 1.f / sum;
#pragma unroll
            for (int q = 0; q < 5; ++q) {
                int c = fr + q * 16;
                if (c < 65) SP[i * 68 + c] = pv[q] * inv;
            }
        }
    }
    __syncthreads();

    // P -> hi/lo bf16 fragment-order (register-staged: ALL reads before barrier,
    // then writes clobber the Q/K+SP alias region)
    int cl = tid >> 3, cj = tid & 7;       // chunk-lane base, j within chunk
    float pr[30];
    {
        int cnt = 0;
#pragma unroll
        for (int rt = 0; rt < 5; ++rt)
#pragma unroll
            for (int kc = 0; kc < 3; ++kc)
#pragma unroll
                for (int s = 0; s < 2; ++s) {
                    int lane2 = cl + s * 32;
                    int row = rt * 16 + (lane2 & 15);
                    int col = kc * 32 + (lane2 >> 4) * 8 + cj;
                    pr[cnt++] = (row < 65 && col < 65) ? SP[row * 68 + col] : 0.f;
                }
    }
    __syncthreads();
    {
        int cnt = 0;
#pragma unroll
        for (int rt = 0; rt < 5; ++rt)
#pragma unroll
            for (int kc = 0; kc < 3; ++kc)
#pragma unroll
                for (int s = 0; s < 2; ++s) {
                    int lane2 = cl + s * 32;
                    float p = pr[cnt++];
                    unsigned short hi = f2b_rne(p);
                    SPu[(rt * 6 + kc) * 512 + lane2 * 8 + cj] = hi;
                    SPu[(rt * 6 + 3 + kc) * 512 + lane2 * 8 + cj] = f2b_rne(p - b2f(hi));
                }
    }
    __syncthreads();

    // PV: 10 tiles (5 rt x 2 ct), K=96 in 3 chunks, conflict-free reads
    unsigned short* ob = o2 + ((size_t)b * NTOK) * DD + h * HDD;
    for (int t = w; t < 10; t += 4) {
        int rt = t >> 1, ct = t & 1;
        f32x4 acc = {0.f, 0.f, 0.f, 0.f};
#pragma unroll
        for (int kc = 0; kc < 3; ++kc) {
            bf16x8 aPh = *(const bf16x8*)&SPu[(rt * 6 + kc) * 512 + lane * 8];
            bf16x8 aPl = *(const bf16x8*)&SPu[(rt * 6 + 3 + kc) * 512 + lane * 8];
            bf16x8 bVh = *(const bf16x8*)&Vh[(ct * 3 + kc) * 512 + lane * 8];
            bf16x8 bVl = *(const bf16x8*)&Vl[(ct * 3 + kc) * 512 + lane * 8];
            acc = __builtin_amdgcn_mfma_f32_16x16x32_bf16(aPh, bVh, acc, 0, 0, 0);
            acc = __builtin_amdgcn_mfma_f32_16x16x32_bf16(aPh, bVl, acc, 0, 0, 0);
            acc = __builtin_amdgcn_mfma_f32_16x16x32_bf16(aPl, bVh, acc, 0, 0, 0);
        }
        int d = ct * 16 + fr;
#pragma unroll
        for (int r = 0; r < 4; ++r) {
            int row = rt * 16 + fc * 4 + r;
            if (row < 65)
                ob[(size_t)row * DD + d] = f2b_rne(acc[r]);
        }
    }
}

// ---------------------------------------------------------------- launch
extern "C" void kernel_launch(void* const* d_in, const int* in_sizes, int n_in,
                              void* d_out, int out_size, void* d_ws, size_t ws_size,
                              hipStream_t stream)
{
    (void)in_sizes; (void)n_in; (void)out_size; (void)ws_size;
    const int*   atom_fea    = (const int*)d_in[0];
    const int*   bond_adj    = (const int*)d_in[1];
    const float* dist_adj    = (const float*)d_in[2];
    const float* atom_tables = (const float*)d_in[3];
    const float* ga_means    = (const float*)d_in[4];
    const float* ga_stds     = (const float*)d_in[5];
    const float* ga_mul      = (const float*)d_in[6];
    const float* ga_bias     = (const float*)d_in[7];
    const float* graph_token = (const float*)d_in[8];
    const float* edge_tables = (const float*)d_in[9];
    const float* gb_means    = (const float*)d_in[10];
    const float* gb_stds     = (const float*)d_in[11];
    const float* gb_mul      = (const float*)d_in[12];
    const float* gb_bias     = (const float*)d_in[13];
    const float* egt         = (const float*)d_in[14];
    const float* in_proj_w   = (const float*)d_in[15];
    const float* in_proj_b   = (const float*)d_in[16];
    const float* out_proj_w  = (const float*)d_in[17];
    const float* out_proj_b  = (const float*)d_in[18];

    const size_t MROWS = (size_t)BB * NTOK;                   // 16640
    char* base = (char*)d_ws;
    unsigned short* x2  = (unsigned short*)base;              // 34.1 MB [16640][1024] (o2 reuses front half)
    float* qkv   = (float*)(base + MROWS * KK2 * 2);          // 102.2 MB [16640][1536]
    float* biasb = (float*)(base + MROWS * KK2 * 2 + MROWS * 3 * DD * 4);      // 69.2 MB
    unsigned short* wq2 = (unsigned short*)((char*)biasb + (size_t)BB * HH * NTOK * NTOK * 4); // 3.1 MB
    unsigned short* wo2 = wq2 + (size_t)3 * DD * KK2;         // 0.5 MB [512][512]

    k_cvt_wdup<<<dim3((3 * DD * DD + 255) / 256), 256, 0, stream>>>(in_proj_w, wq2, 3 * DD * DD);
    k_cvt_w<<<dim3((DD * DD + 255) / 256), 256, 0, stream>>>(out_proj_w, wo2, DD * DD);
    k_atom_embed<<<dim3(NTOK, BB), 256, 0, stream>>>(atom_fea, atom_tables, ga_means,
                                                     ga_stds, ga_mul, ga_bias, graph_token, x2);
    k_edge_bias<<<dim3(BB), 1024, 0, stream>>>(bond_adj, dist_adj, edge_tables, gb_means,
                                               gb_stds, gb_mul, gb_bias, egt, biasb);
    k_gemm_mfma<<<dim3(130, 12), 256, 0, stream>>>(x2, wq2, in_proj_b, qkv,
                                                   (int)MROWS, 3 * DD, KK2);
    k_attn<<<dim3(HH, BB), 256, 0, stream>>>(qkv, biasb, x2 /* o2: [16640][512] bf16 */);
    k_gemm_mfma<<<dim3(130, 4), 256, 0, stream>>>(x2, wo2, out_proj_b, (float*)d_out,
                                                  (int)MROWS, DD, DD);
}